// Round 6
// baseline (308.532 us; speedup 1.0000x reference)
//
#include <hip/hip_runtime.h>
#include <math.h>

typedef __attribute__((ext_vector_type(8))) short short8;
typedef __attribute__((ext_vector_type(4))) float f32x4;
typedef __attribute__((ext_vector_type(2))) float f32x2;

#define LRELU(x) ((x) > 0.0f ? (x) : 0.01f * (x))

struct __align__(4) Int3 { int x, y, z; };

__device__ __forceinline__ unsigned short f2bf(float f) {
    unsigned int u = __float_as_uint(f);
    return (unsigned short)((u + 0x7FFFu + ((u >> 16) & 1u)) >> 16);
}
__device__ __forceinline__ unsigned int pack_bf16_pair(float lo, float hi) {
    unsigned int ul = __float_as_uint(lo) + 0x8000u;
    unsigned int uh = __float_as_uint(hi) + 0x8000u;
    return (ul >> 16) | (uh & 0xFFFF0000u);
}
__device__ __forceinline__ float2 stats_from(const float* sums, int b, float count) {
    float s = sums[2 * b], q = sums[2 * b + 1];
    float mean = s / count;
    float var = (q - s * s / count) / (count - 1.0f);  // ddof=1
    var = fmaxf(var, 0.0f);
    return make_float2(mean, 1.0f / (sqrtf(var) + 1e-5f));
}
// init pattern 0xFFFFFFFF (-NaN): positives via signed max, negatives via unsigned min
__device__ __forceinline__ void atomicMaxF(float* a, float v) {
    if (v >= 0.0f) atomicMax((int*)a, __float_as_int(v));
    else           atomicMin((unsigned int*)a, __float_as_uint(v));
}
// 4 fp8 e4m3 -> lrelu(x*a+c) -> 4 fp8 e4m3 (in-register, for the norm_act passes)
__device__ __forceinline__ unsigned int fp8x4_nact(unsigned int u, float a, float c) {
    f32x2 lo = __builtin_amdgcn_cvt_pk_f32_fp8(u, false);
    f32x2 hi = __builtin_amdgcn_cvt_pk_f32_fp8(u, true);
    lo = lo * a + c; hi = hi * a + c;
    f32x2 ml = lo * 0.01f, mh = hi * 0.01f;
    lo = __builtin_elementwise_max(lo, ml);
    hi = __builtin_elementwise_max(hi, mh);
    int r = __builtin_amdgcn_cvt_pk_fp8_f32(lo.x, lo.y, 0, false);
    r = __builtin_amdgcn_cvt_pk_fp8_f32(hi.x, hi.y, r, true);
    return (unsigned int)r;
}
// R15 k-byte permutation within each 128-byte chunk: fp8 fragment pairs land on
// one contiguous 16B column -> ds_read_b128, bf16-identical 0-conflict geometry.
__device__ __forceinline__ int perm128(int o) {
    return ((o >> 6) << 6) | (((o >> 3) & 3) << 4) | (((o >> 5) & 1) << 3) | (o & 7);
}

// MFMA fragment block (bf16): LDS -> frags -> 2 k-stages of 16x16x32 bf16 MFMAs
template <int MT, int WM>
__device__ __forceinline__ void mfma_step(const unsigned short* wt, const unsigned short* gt,
                                          f32x4 (&acc)[MT][4],
                                          int wo, int wn, int quad, int l15, int blkid)
{
#pragma unroll
    for (int st = 0; st < 2; ++st) {
        short8 af[MT], bfv[4];
        const int qb = st * 4 + quad;
#pragma unroll
        for (int i = 0; i < MT; i++) {
            const int orow = wo * WM + i * 16 + l15;
            af[i] = *(const short8*)&wt[orow * 64 + ((qb ^ blkid) << 3)];
        }
#pragma unroll
        for (int t = 0; t < 4; t++) {
            const int nrow = wn * 64 + t * 16 + l15;
            bfv[t] = *(const short8*)&gt[nrow * 64 + ((qb ^ blkid) << 3)];
        }
#pragma unroll
        for (int i = 0; i < MT; i++)
#pragma unroll
            for (int t = 0; t < 4; t++)
                acc[i][t] = __builtin_amdgcn_mfma_f32_16x16x32_bf16(
                    af[i], bfv[t], acc[i][t], 0, 0, 0);
    }
}

// w1 -> bf16 [256][192]; w2 -> fp8 [128][768] k-permuted; w3 -> fp8 [64][384] k-permuted
__global__ void prep_all(const float* __restrict__ w1, unsigned short* __restrict__ wq1,
                         const float* __restrict__ w2, unsigned char* __restrict__ wq2,
                         const float* __restrict__ w3, unsigned char* __restrict__ wq3)
{
    const int tid = blockIdx.x * blockDim.x + threadIdx.x;
    const int stride = gridDim.x * blockDim.x;
    for (int i = tid; i < 256 * 192; i += stride) {
        int o = i / 192, kp = i - o * 192;
        int j = kp >> 6, c = kp & 63;
        wq1[i] = f2bf(w1[(o * 64 + c) * 3 + j]);
    }
    // dest byte r0 within row -> inverse perm -> orig k' (4 consecutive share j)
    for (int i = tid; i < (128 * 768) >> 2; i += stride) {
        const int e0 = i << 2;
        const int o = e0 / 768, r0 = e0 - o * 768;
        const int kc = r0 >> 7, ro = r0 & 127;
        const int k0 = ((ro >> 6) << 6) + (((ro >> 3) & 1) << 5) + (((ro >> 4) & 3) << 3) + (ro & 7);
        const int kp0 = kc * 128 + k0;
        const int j = kp0 >> 8, c0 = kp0 & 255;
        const float* src = &w2[(o * 256 + c0) * 3 + j];
        float f0 = src[0], f1 = src[3], f2 = src[6], f3 = src[9];
        int r = __builtin_amdgcn_cvt_pk_fp8_f32(f0, f1, 0, false);
        r = __builtin_amdgcn_cvt_pk_fp8_f32(f2, f3, r, true);
        *(unsigned int*)&wq2[e0] = (unsigned int)r;
    }
    for (int i = tid; i < (64 * 384) >> 2; i += stride) {
        const int e0 = i << 2;
        const int o = e0 / 384, r0 = e0 - o * 384;
        const int kc = r0 >> 7, ro = r0 & 127;
        const int k0 = ((ro >> 6) << 6) + (((ro >> 3) & 1) << 5) + (((ro >> 4) & 3) << 3) + (ro & 7);
        const int kp0 = kc * 128 + k0;
        const int j = kp0 >> 7, c0 = kp0 & 127;
        const float* src = &w3[(o * 128 + c0) * 3 + j];
        float f0 = src[0], f1 = src[3], f2 = src[6], f3 = src[9];
        int r = __builtin_amdgcn_cvt_pk_fp8_f32(f0, f1, 0, false);
        r = __builtin_amdgcn_cvt_pk_fp8_f32(f2, f3, r, true);
        *(unsigned int*)&wq3[e0] = (unsigned int)r;
    }
}

// data [128][64][1024] f32 -> xT [nB][1024][64] bf16 (tower select on b>=128)
// block (0,0) also re-inits sums/pmax (replaces 2 hipMemsetAsync dispatches)
__global__ __launch_bounds__(256) void transpose_in(const float* __restrict__ inA,
                                                    const float* __restrict__ inB,
                                                    unsigned short* __restrict__ xT,
                                                    float* __restrict__ sums,
                                                    unsigned int* __restrict__ pmax)
{
    const int b = blockIdx.y, n0 = blockIdx.x * 64;
    const float* in = (b >= 128 ? inB : inA) + ((size_t)(b & 127) * 64) * 1024;
    const int tid = threadIdx.x;
    if (blockIdx.x == 0 && blockIdx.y == 0) {
        const int nBv = gridDim.y;
        for (int i = tid; i < 3 * nBv * 2; i += 256) sums[i] = 0.0f;
        for (int i = tid; i < nBv * 64; i += 256) pmax[i] = 0xFFFFFFFFu;
    }
    __shared__ float tile[64][65];
    const int nn = tid & 63, cw = tid >> 6;
#pragma unroll
    for (int i = 0; i < 16; i++) {
        int c = i * 4 + cw;
        tile[c][nn] = in[(size_t)c * 1024 + n0 + nn];
    }
    __syncthreads();
    const int n = tid >> 2, cp = (tid & 3) * 16;
    unsigned int pk[8];
#pragma unroll
    for (int i = 0; i < 8; i++) {
        unsigned short lo = f2bf(tile[cp + 2 * i][n]);
        unsigned short hi = f2bf(tile[cp + 2 * i + 1][n]);
        pk[i] = (unsigned int)lo | ((unsigned int)hi << 16);
    }
    unsigned short* dst = xT + ((size_t)b * 1024 + n0 + n) * 64 + cp;
    uint4 v0 = {pk[0], pk[1], pk[2], pk[3]};
    uint4 v1 = {pk[4], pk[5], pk[6], pk[7]};
    *(uint4*)dst = v0;
    *(uint4*)(dst + 8) = v1;
}

// apply lrelu(norm(.)) ONCE per element (in place). u4PerB = uint4s per batch row.
__global__ __launch_bounds__(256) void norm_act_fp8(unsigned char* __restrict__ a,
                                                    const float* __restrict__ sums,
                                                    float count, int u4PerB)
{
    const int b = blockIdx.y;
    float2 st = stats_from(sums, b, count);
    const float na = st.y, nc = -st.x * st.y;
    uint4* p = (uint4*)a + (size_t)b * u4PerB;
    for (int idx = blockIdx.x * 256 + threadIdx.x; idx < u4PerB; idx += gridDim.x * 256) {
        uint4 v = p[idx];
        v.x = fp8x4_nact(v.x, na, nc);
        v.y = fp8x4_nact(v.y, na, nc);
        v.z = fp8x4_nact(v.z, na, nc);
        v.w = fp8x4_nact(v.w, na, nc);
        p[idx] = v;
    }
}

// R16: TA(request)-model round 2 -- bigger tiles amortize weight re-reads and
// dedupe gathers. conv1: o-halves merged (512 thr, 8 waves, gathers shared);
// vmem instrs -21%. All k-loop/swizzle geometry unchanged from verified R15.
__global__ __launch_bounds__(512, 2) void conv1_mfma(
    const unsigned short* __restrict__ xT,   // [nB][1024][64] bf16
    const int* __restrict__ idxA,            // [128][3069]
    const int* __restrict__ idxB,
    const unsigned short* __restrict__ wq,   // [256][192] bf16 (k'=j*64+c)
    const float* __restrict__ bias,          // [256] f32
    unsigned char* __restrict__ out,         // [nB][1024][256] fp8 raw (k-permuted)
    float* __restrict__ sums)                // [nB][2]
{
    const int b   = blockIdx.x;
    const int nt0 = blockIdx.z << 7;
    const int tid = threadIdx.x;
    const int lane = tid & 63, wave = tid >> 6;   // 8 waves
    const int wo = wave & 3, wn = wave >> 2;      // o: 4x64=256, n: 2x64=128
    const int quad = lane >> 4, l15 = lane & 15;
    const int blkid = lane & 7;

    __shared__ __align__(16) unsigned short wt[256 * 64];   // 32KB
    __shared__ __align__(16) unsigned short gt[128 * 64];   // 16KB

    f32x4 acc[4][4];
#pragma unroll
    for (int i = 0; i < 4; i++)
#pragma unroll
        for (int t = 0; t < 4; t++) acc[i][t] = (f32x4){0.f, 0.f, 0.f, 0.f};

    const unsigned short* xTb = xT + (((size_t)b) << 10) * 64;
    const int* idxb = (b >= 128 ? idxB : idxA) + (size_t)(b & 127) * 3069;

    // gather: 4 threads/row, 32B quarters
    const int gr = tid >> 2, gh = tid & 3;
    int s0, s1, s2;
    {
        int n = nt0 + gr;
        int t0 = (n == 0) ? 0 : (n - 1);
        const Int3 sv = *(const Int3*)&idxb[3 * t0];
        s0 = sv.x; s1 = sv.y; s2 = sv.z;
    }
    // weights: 2 threads/row, 64B halves
    const int wr = tid >> 1, wseg = tid & 1;
    const unsigned short* wrow = wq + (size_t)wr * 192 + wseg * 32;
    const int gswz = gr & 7, wswz = wr & 7;

    uint4 g0A, g1A, g0B, g1B;

#define LOADC(S, KC) {                                                           \
        const int src_ = ((KC) == 0) ? s0 : (((KC) == 1) ? s1 : s2);             \
        const uint4* gp_ = (const uint4*)(xTb + (size_t)src_ * 64 + gh * 16);    \
        g0##S = gp_[0]; g1##S = gp_[1];                                          \
    }

#define STAGE(S, KC) {                                                           \
        const uint4* wp_ = (const uint4*)(wrow + ((KC) << 6));                   \
        uint4 wv0 = wp_[0], wv1 = wp_[1], wv2 = wp_[2], wv3 = wp_[3];            \
        *(uint4*)&gt[gr * 64 + (((gh << 1) | 0) ^ gswz) * 8] = g0##S;            \
        *(uint4*)&gt[gr * 64 + (((gh << 1) | 1) ^ gswz) * 8] = g1##S;            \
        *(uint4*)&wt[wr * 64 + ((wseg * 4 + 0) ^ wswz) * 8] = wv0;               \
        *(uint4*)&wt[wr * 64 + ((wseg * 4 + 1) ^ wswz) * 8] = wv1;               \
        *(uint4*)&wt[wr * 64 + ((wseg * 4 + 2) ^ wswz) * 8] = wv2;               \
        *(uint4*)&wt[wr * 64 + ((wseg * 4 + 3) ^ wswz) * 8] = wv3;               \
    }

    // 3 chunks, 2-deep register pipeline, odd tail
    LOADC(A, 0);
    LOADC(B, 1);
    int kc = 0;
    for (; kc + 2 <= 3; kc += 2) {
        if (kc) __syncthreads();
        STAGE(A, kc);
        if (kc + 2 < 3) LOADC(A, kc + 2);
        __syncthreads();
        mfma_step<4, 64>(wt, gt, acc, wo, wn, quad, l15, blkid);
        __syncthreads();
        STAGE(B, kc + 1);
        __syncthreads();
        mfma_step<4, 64>(wt, gt, acc, wo, wn, quad, l15, blkid);
    }
    {   // tail chunk 2 (set A)
        __syncthreads();
        STAGE(A, 2);
        __syncthreads();
        mfma_step<4, 64>(wt, gt, acc, wo, wn, quad, l15, blkid);
    }
#undef LOADC
#undef STAGE

    __syncthreads();                 // all LDS readers done
    unsigned char* eb = (unsigned char*)wt;   // [128 n][256 o'] fp8, swizzled (32KB)
    float lsum = 0.f, lsq = 0.f;
#pragma unroll
    for (int i = 0; i < 4; i++) {
        const int obl = wo * 64 + i * 16 + quad * 4;   // 0..255
        const int op  = perm128(obl);                  // per-128 chunk perm (bit7 kept)
        const float4 bv = *(const float4*)(bias + obl);
#pragma unroll
        for (int t = 0; t < 4; t++) {
            const int nl = wn * 64 + t * 16 + l15;     // 0..127
            float v0 = acc[i][t][0] + bv.x;
            float v1 = acc[i][t][1] + bv.y;
            float v2 = acc[i][t][2] + bv.z;
            float v3 = acc[i][t][3] + bv.w;
            if (nt0 + nl == 0) { v0 = v1 = v2 = v3 = 0.f; }
            lsum += v0 + v1 + v2 + v3;
            lsq  += v0 * v0 + v1 * v1 + v2 * v2 + v3 * v3;
            int r = __builtin_amdgcn_cvt_pk_fp8_f32(v0, v1, 0, false);
            r = __builtin_amdgcn_cvt_pk_fp8_f32(v2, v3, r, true);
            *(unsigned int*)&eb[nl * 256 + (op ^ ((nl & 7) << 4))] = (unsigned int)r;
        }
    }
#pragma unroll
    for (int off = 32; off > 0; off >>= 1) {
        lsum += __shfl_down(lsum, off);
        lsq  += __shfl_down(lsq, off);
    }
    float* red = (float*)gt;
    if (lane == 0) { red[wave] = lsum; red[8 + wave] = lsq; }
    __syncthreads();
    // dense store: 128 rows x 256B -> 64B/thread
    {
        const int row = tid >> 2, c0 = (tid & 3) * 64;
#pragma unroll
        for (int i = 0; i < 4; ++i) {
            const int off = c0 + i * 16;
            uint4 v = *(const uint4*)&eb[row * 256 + (off ^ ((row & 7) << 4))];
            *(uint4*)&out[((size_t)b * 1024 + nt0 + row) * 256 + off] = v;
        }
    }
    if (tid == 0) {
        float a0 = 0.f, a1 = 0.f;
#pragma unroll
        for (int w = 0; w < 8; ++w) { a0 += red[w]; a1 += red[8 + w]; }
        atomicAdd(&sums[2 * b + 0], a0);
        atomicAdd(&sums[2 * b + 1], a1);
    }
}

// conv2: pure-copy-stage fp8 x fp8 MFMA, k-permuted, b128 fragment reads.
// R16: 256-row n-tiles (z=4), 512 threads -> weight re-reads per row halved.
__global__ __launch_bounds__(512, 2) void conv2_fp8(
    const unsigned char* __restrict__ a1,    // [nB][1024][256] fp8, normalized, permuted
    const int* __restrict__ idxA,
    const int* __restrict__ idxB,
    const unsigned char* __restrict__ wq8,   // [128][768] fp8 e4m3, k-permuted
    const float* __restrict__ bias,          // [128] f32
    unsigned char* __restrict__ out,         // [nB][1024][128] fp8 raw (permuted)
    float* __restrict__ sums)                // [nB][2]
{
    const int b   = blockIdx.x;
    const int nt0 = blockIdx.z << 8;              // 256-row tiles
    const int tid = threadIdx.x;
    const int lane = tid & 63, wave = tid >> 6;   // 8 waves
    const int wo = wave & 1, wn = wave >> 1;      // o: 2x64, n: 4x64=256
    const int quad = lane >> 4, l15 = lane & 15;
    const int blkid = lane & 7;

    __shared__ __align__(16) unsigned char wt8[128 * 128];  // 16KB
    __shared__ __align__(16) unsigned char gt8[256 * 128];  // 32KB

    f32x4 acc[4][4];
#pragma unroll
    for (int i = 0; i < 4; i++)
#pragma unroll
        for (int t = 0; t < 4; t++) acc[i][t] = (f32x4){0.f, 0.f, 0.f, 0.f};

    const unsigned char* xb = a1 + (((size_t)b) << 10) * 256;
    const int* idxb = (b >= 128 ? idxB : idxA) + (size_t)(b & 127) * 3069;

    // gather: 2 threads/row (64B halves), 256 rows
    const int gr = tid >> 1, gh = tid & 1;
    int si0, si1, si2;
    {
        int n = nt0 + gr;
        int t0 = (n == 0) ? 0 : (n - 1);
        const Int3 sv = *(const Int3*)&idxb[3 * t0];
        si0 = sv.x; si1 = sv.y; si2 = sv.z;
    }
    // weights: 4 threads/row (32B segments), 128 rows
    const int wr = tid >> 2, wseg = tid & 3;
    const unsigned char* wrow = wq8 + (size_t)wr * 768 + wseg * 32;
    const int gswz = gr & 7, wswz = wr & 7;

    uint4 g0A, g1A, g2A, g3A;
    uint4 g0B, g1B, g2B, g3B;

#define LOADC2(S, KC) {                                                          \
        const int j_  = (KC) >> 1;                                               \
        const int c0_ = ((KC) & 1) << 7;                                         \
        const int src_ = (j_ == 0) ? si0 : ((j_ == 1) ? si1 : si2);              \
        const uint4* gp_ = (const uint4*)(xb + (size_t)src_ * 256 + c0_ + gh * 64); \
        g0##S = gp_[0]; g1##S = gp_[1]; g2##S = gp_[2]; g3##S = gp_[3];          \
    }

#define STAGE2(S, KC) {                                                          \
        const uint4* wp_ = (const uint4*)(wrow + (KC) * 128);                    \
        uint4 wv0 = wp_[0], wv1 = wp_[1];                                        \
        *(uint4*)&gt8[gr * 128 + (((gh << 2) | 0) ^ gswz) * 16] = g0##S;         \
        *(uint4*)&gt8[gr * 128 + (((gh << 2) | 1) ^ gswz) * 16] = g1##S;         \
        *(uint4*)&gt8[gr * 128 + (((gh << 2) | 2) ^ gswz) * 16] = g2##S;         \
        *(uint4*)&gt8[gr * 128 + (((gh << 2) | 3) ^ gswz) * 16] = g3##S;         \
        *(uint4*)&wt8[wr * 128 + (((wseg << 1) | 0) ^ wswz) * 16] = wv0;         \
        *(uint4*)&wt8[wr * 128 + (((wseg << 1) | 1) ^ wswz) * 16] = wv1;         \
    }

#define MFMA_STEP2 {                                                             \
        _Pragma("unroll")                                                        \
        for (int pp = 0; pp < 2; ++pp) {                                         \
            ulonglong2 a0v, a1v, a2v, a3v, b0v, b1v, b2v, b3v;                   \
            {                                                                    \
                const int cx = (((pp * 4 + quad) ^ blkid) << 4);                 \
                a0v = *(const ulonglong2*)&wt8[(wo * 64 +  0 + l15) * 128 + cx]; \
                a1v = *(const ulonglong2*)&wt8[(wo * 64 + 16 + l15) * 128 + cx]; \
                a2v = *(const ulonglong2*)&wt8[(wo * 64 + 32 + l15) * 128 + cx]; \
                a3v = *(const ulonglong2*)&wt8[(wo * 64 + 48 + l15) * 128 + cx]; \
                b0v = *(const ulonglong2*)&gt8[(wn * 64 +  0 + l15) * 128 + cx]; \
                b1v = *(const ulonglong2*)&gt8[(wn * 64 + 16 + l15) * 128 + cx]; \
                b2v = *(const ulonglong2*)&gt8[(wn * 64 + 32 + l15) * 128 + cx]; \
                b3v = *(const ulonglong2*)&gt8[(wn * 64 + 48 + l15) * 128 + cx]; \
            }                                                                    \
            acc[0][0] = __builtin_amdgcn_mfma_f32_16x16x32_fp8_fp8((long)a0v.x, (long)b0v.x, acc[0][0], 0, 0, 0); \
            acc[0][1] = __builtin_amdgcn_mfma_f32_16x16x32_fp8_fp8((long)a0v.x, (long)b1v.x, acc[0][1], 0, 0, 0); \
            acc[0][2] = __builtin_amdgcn_mfma_f32_16x16x32_fp8_fp8((long)a0v.x, (long)b2v.x, acc[0][2], 0, 0, 0); \
            acc[0][3] = __builtin_amdgcn_mfma_f32_16x16x32_fp8_fp8((long)a0v.x, (long)b3v.x, acc[0][3], 0, 0, 0); \
            acc[1][0] = __builtin_amdgcn_mfma_f32_16x16x32_fp8_fp8((long)a1v.x, (long)b0v.x, acc[1][0], 0, 0, 0); \
            acc[1][1] = __builtin_amdgcn_mfma_f32_16x16x32_fp8_fp8((long)a1v.x, (long)b1v.x, acc[1][1], 0, 0, 0); \
            acc[1][2] = __builtin_amdgcn_mfma_f32_16x16x32_fp8_fp8((long)a1v.x, (long)b2v.x, acc[1][2], 0, 0, 0); \
            acc[1][3] = __builtin_amdgcn_mfma_f32_16x16x32_fp8_fp8((long)a1v.x, (long)b3v.x, acc[1][3], 0, 0, 0); \
            acc[2][0] = __builtin_amdgcn_mfma_f32_16x16x32_fp8_fp8((long)a2v.x, (long)b0v.x, acc[2][0], 0, 0, 0); \
            acc[2][1] = __builtin_amdgcn_mfma_f32_16x16x32_fp8_fp8((long)a2v.x, (long)b1v.x, acc[2][1], 0, 0, 0); \
            acc[2][2] = __builtin_amdgcn_mfma_f32_16x16x32_fp8_fp8((long)a2v.x, (long)b2v.x, acc[2][2], 0, 0, 0); \
            acc[2][3] = __builtin_amdgcn_mfma_f32_16x16x32_fp8_fp8((long)a2v.x, (long)b3v.x, acc[2][3], 0, 0, 0); \
            acc[3][0] = __builtin_amdgcn_mfma_f32_16x16x32_fp8_fp8((long)a3v.x, (long)b0v.x, acc[3][0], 0, 0, 0); \
            acc[3][1] = __builtin_amdgcn_mfma_f32_16x16x32_fp8_fp8((long)a3v.x, (long)b1v.x, acc[3][1], 0, 0, 0); \
            acc[3][2] = __builtin_amdgcn_mfma_f32_16x16x32_fp8_fp8((long)a3v.x, (long)b2v.x, acc[3][2], 0, 0, 0); \
            acc[3][3] = __builtin_amdgcn_mfma_f32_16x16x32_fp8_fp8((long)a3v.x, (long)b3v.x, acc[3][3], 0, 0, 0); \
            acc[0][0] = __builtin_amdgcn_mfma_f32_16x16x32_fp8_fp8((long)a0v.y, (long)b0v.y, acc[0][0], 0, 0, 0); \
            acc[0][1] = __builtin_amdgcn_mfma_f32_16x16x32_fp8_fp8((long)a0v.y, (long)b1v.y, acc[0][1], 0, 0, 0); \
            acc[0][2] = __builtin_amdgcn_mfma_f32_16x16x32_fp8_fp8((long)a0v.y, (long)b2v.y, acc[0][2], 0, 0, 0); \
            acc[0][3] = __builtin_amdgcn_mfma_f32_16x16x32_fp8_fp8((long)a0v.y, (long)b3v.y, acc[0][3], 0, 0, 0); \
            acc[1][0] = __builtin_amdgcn_mfma_f32_16x16x32_fp8_fp8((long)a1v.y, (long)b0v.y, acc[1][0], 0, 0, 0); \
            acc[1][1] = __builtin_amdgcn_mfma_f32_16x16x32_fp8_fp8((long)a1v.y, (long)b1v.y, acc[1][1], 0, 0, 0); \
            acc[1][2] = __builtin_amdgcn_mfma_f32_16x16x32_fp8_fp8((long)a1v.y, (long)b2v.y, acc[1][2], 0, 0, 0); \
            acc[1][3] = __builtin_amdgcn_mfma_f32_16x16x32_fp8_fp8((long)a1v.y, (long)b3v.y, acc[1][3], 0, 0, 0); \
            acc[2][0] = __builtin_amdgcn_mfma_f32_16x16x32_fp8_fp8((long)a2v.y, (long)b0v.y, acc[2][0], 0, 0, 0); \
            acc[2][1] = __builtin_amdgcn_mfma_f32_16x16x32_fp8_fp8((long)a2v.y, (long)b1v.y, acc[2][1], 0, 0, 0); \
            acc[2][2] = __builtin_amdgcn_mfma_f32_16x16x32_fp8_fp8((long)a2v.y, (long)b2v.y, acc[2][2], 0, 0, 0); \
            acc[2][3] = __builtin_amdgcn_mfma_f32_16x16x32_fp8_fp8((long)a2v.y, (long)b3v.y, acc[2][3], 0, 0, 0); \
            acc[3][0] = __builtin_amdgcn_mfma_f32_16x16x32_fp8_fp8((long)a3v.y, (long)b0v.y, acc[3][0], 0, 0, 0); \
            acc[3][1] = __builtin_amdgcn_mfma_f32_16x16x32_fp8_fp8((long)a3v.y, (long)b1v.y, acc[3][1], 0, 0, 0); \
            acc[3][2] = __builtin_amdgcn_mfma_f32_16x16x32_fp8_fp8((long)a3v.y, (long)b2v.y, acc[3][2], 0, 0, 0); \
            acc[3][3] = __builtin_amdgcn_mfma_f32_16x16x32_fp8_fp8((long)a3v.y, (long)b3v.y, acc[3][3], 0, 0, 0); \
        }                                                                        \
    }

    LOADC2(A, 0);
    LOADC2(B, 1);
    int kc = 0;
    for (; kc + 2 <= 6; kc += 2) {
        if (kc) __syncthreads();
        STAGE2(A, kc);
        if (kc + 2 < 6) LOADC2(A, kc + 2);
        __syncthreads();
        MFMA_STEP2;
        __syncthreads();
        STAGE2(B, kc + 1);
        if (kc + 3 < 6) LOADC2(B, kc + 3);
        __syncthreads();
        MFMA_STEP2;
    }
#undef LOADC2
#undef STAGE2
#undef MFMA_STEP2

    __syncthreads();                 // all LDS readers done
    unsigned char* eb = gt8;         // [256 n][128 o'] fp8, swizzled (32KB)
    float lsum = 0.f, lsq = 0.f;
#pragma unroll
    for (int i = 0; i < 4; i++) {
        const int obl = wo * 64 + i * 16 + quad * 4;
        const int op  = perm128(obl);
        const float4 bv = *(const float4*)(bias + obl);
#pragma unroll
        for (int t = 0; t < 4; t++) {
            const int nl = wn * 64 + t * 16 + l15;     // 0..255
            float v0 = acc[i][t][0] + bv.x;
            float v1 = acc[i][t][1] + bv.y;
            float v2 = acc[i][t][2] + bv.z;
            float v3 = acc[i][t][3] + bv.w;
            if (nt0 + nl == 0) { v0 = v1 = v2 = v3 = 0.f; }
            lsum += v0 + v1 + v2 + v3;
            lsq  += v0 * v0 + v1 * v1 + v2 * v2 + v3 * v3;
            int r = __builtin_amdgcn_cvt_pk_fp8_f32(v0, v1, 0, false);
            r = __builtin_amdgcn_cvt_pk_fp8_f32(v2, v3, r, true);
            *(unsigned int*)&eb[nl * 128 + (op ^ ((nl & 7) << 4))] = (unsigned int)r;
        }
    }
#pragma unroll
    for (int off = 32; off > 0; off >>= 1) {
        lsum += __shfl_down(lsum, off);
        lsq  += __shfl_down(lsq, off);
    }
    float* red = (float*)wt8;
    if (lane == 0) { red[wave] = lsum; red[8 + wave] = lsq; }
    __syncthreads();
    // dense store: 256 rows x 128B -> 64B/thread
    {
        const int row = tid >> 1, c0 = (tid & 1) * 64;
#pragma unroll
        for (int i = 0; i < 4; ++i) {
            const int off = c0 + i * 16;
            uint4 v = *(const uint4*)&eb[row * 128 + (off ^ ((row & 7) << 4))];
            *(uint4*)&out[((size_t)b * 1024 + nt0 + row) * 128 + off] = v;
        }
    }
    if (tid == 0) {
        float a0 = 0.f, a1v = 0.f;
#pragma unroll
        for (int w = 0; w < 8; ++w) { a0 += red[w]; a1v += red[8 + w]; }
        atomicAdd(&sums[2 * b + 0], a0);
        atomicAdd(&sums[2 * b + 1], a1v);
    }
}

// conv3: pure-copy fp8 x fp8 MFMA on k-permuted a2, 256-row tiles, POOL epilogue.
__global__ __launch_bounds__(512, 2) void conv3_fp8(
    const unsigned char* __restrict__ a2,    // [nB][1024][128] fp8, normalized, permuted
    const int* __restrict__ idxA,
    const int* __restrict__ idxB,
    const unsigned char* __restrict__ wq8,   // [64][384] fp8 e4m3, k-permuted
    const float* __restrict__ bias,          // [64] f32
    float* __restrict__ sums,                // [nB][2]
    float* __restrict__ pmax)                // [nB][64]
{
    const int b   = blockIdx.x;
    const int nt0 = blockIdx.z << 8;              // 256-row tiles
    const int tid = threadIdx.x;
    const int lane = tid & 63, wave = tid >> 6;   // 8 waves
    const int wo = wave & 1, wn = wave >> 1;      // o: 2x32, n: 4x64=256
    const int quad = lane >> 4, l15 = lane & 15;
    const int blkid = lane & 7;

    __shared__ __align__(16) unsigned char wt8[64 * 128];   // 8KB
    __shared__ __align__(16) unsigned char gt8[256 * 128];  // 32KB

    f32x4 acc[2][4];
#pragma unroll
    for (int i = 0; i < 2; i++)
#pragma unroll
        for (int t = 0; t < 4; t++) acc[i][t] = (f32x4){0.f, 0.f, 0.f, 0.f};

    const unsigned char* xb = a2 + (((size_t)b) << 10) * 128;
    const int* idxb = (b >= 128 ? idxB : idxA) + (size_t)(b & 127) * 3069;

    const int gr = tid >> 1, gh = tid & 1;       // 2 threads/row, 64B halves
    int si0, si1, si2;
    {
        int n = nt0 + gr;
        int t0 = (n == 0) ? 0 : (n - 1);
        const Int3 sv = *(const Int3*)&idxb[3 * t0];
        si0 = sv.x; si1 = sv.y; si2 = sv.z;
    }
    const int wr = tid >> 3, wseg = tid & 7;     // 8 threads/row, 16B segments
    const unsigned char* wrow = wq8 + (size_t)wr * 384 + wseg * 16;
    const int gswz = gr & 7, wswz = wr & 7;

    uint4 g0A, g1A, g2A, g3A;
    uint4 g0B, g1B, g2B, g3B;

#define LOADC3(S, KC) {                                                          \
        const int src_ = ((KC) == 0) ? si0 : (((KC) == 1) ? si1 : si2);          \
        const uint4* gp_ = (const uint4*)(xb + (size_t)src_ * 128 + gh * 64);    \
        g0##S = gp_[0]; g1##S = gp_[1]; g2##S = gp_[2]; g3##S = gp_[3];          \
    }

#define STAGE3(S, KC) {                                                          \
        uint4 wv0 = *(const uint4*)(wrow + (KC) * 128);                          \
        *(uint4*)&gt8[gr * 128 + (((gh << 2) | 0) ^ gswz) * 16] = g0##S;         \
        *(uint4*)&gt8[gr * 128 + (((gh << 2) | 1) ^ gswz) * 16] = g1##S;         \
        *(uint4*)&gt8[gr * 128 + (((gh << 2) | 2) ^ gswz) * 16] = g2##S;         \
        *(uint4*)&gt8[gr * 128 + (((gh << 2) | 3) ^ gswz) * 16] = g3##S;         \
        *(uint4*)&wt8[wr * 128 + (wseg ^ wswz) * 16] = wv0;                      \
    }

#define MFMA_STEP3 {                                                             \
        _Pragma("unroll")                                                        \
        for (int pp = 0; pp < 2; ++pp) {                                         \
            ulonglong2 a0v, a1v, b0v, b1v, b2v, b3v;                             \
            {                                                                    \
                const int cx = (((pp * 4 + quad) ^ blkid) << 4);                 \
                a0v = *(const ulonglong2*)&wt8[(wo * 32 +  0 + l15) * 128 + cx]; \
                a1v = *(const ulonglong2*)&wt8[(wo * 32 + 16 + l15) * 128 + cx]; \
                b0v = *(const ulonglong2*)&gt8[(wn * 64 +  0 + l15) * 128 + cx]; \
                b1v = *(const ulonglong2*)&gt8[(wn * 64 + 16 + l15) * 128 + cx]; \
                b2v = *(const ulonglong2*)&gt8[(wn * 64 + 32 + l15) * 128 + cx]; \
                b3v = *(const ulonglong2*)&gt8[(wn * 64 + 48 + l15) * 128 + cx]; \
            }                                                                    \
            acc[0][0] = __builtin_amdgcn_mfma_f32_16x16x32_fp8_fp8((long)a0v.x, (long)b0v.x, acc[0][0], 0, 0, 0); \
            acc[0][1] = __builtin_amdgcn_mfma_f32_16x16x32_fp8_fp8((long)a0v.x, (long)b1v.x, acc[0][1], 0, 0, 0); \
            acc[0][2] = __builtin_amdgcn_mfma_f32_16x16x32_fp8_fp8((long)a0v.x, (long)b2v.x, acc[0][2], 0, 0, 0); \
            acc[0][3] = __builtin_amdgcn_mfma_f32_16x16x32_fp8_fp8((long)a0v.x, (long)b3v.x, acc[0][3], 0, 0, 0); \
            acc[1][0] = __builtin_amdgcn_mfma_f32_16x16x32_fp8_fp8((long)a1v.x, (long)b0v.x, acc[1][0], 0, 0, 0); \
            acc[1][1] = __builtin_amdgcn_mfma_f32_16x16x32_fp8_fp8((long)a1v.x, (long)b1v.x, acc[1][1], 0, 0, 0); \
            acc[1][2] = __builtin_amdgcn_mfma_f32_16x16x32_fp8_fp8((long)a1v.x, (long)b2v.x, acc[1][2], 0, 0, 0); \
            acc[1][3] = __builtin_amdgcn_mfma_f32_16x16x32_fp8_fp8((long)a1v.x, (long)b3v.x, acc[1][3], 0, 0, 0); \
            acc[0][0] = __builtin_amdgcn_mfma_f32_16x16x32_fp8_fp8((long)a0v.y, (long)b0v.y, acc[0][0], 0, 0, 0); \
            acc[0][1] = __builtin_amdgcn_mfma_f32_16x16x32_fp8_fp8((long)a0v.y, (long)b1v.y, acc[0][1], 0, 0, 0); \
            acc[0][2] = __builtin_amdgcn_mfma_f32_16x16x32_fp8_fp8((long)a0v.y, (long)b2v.y, acc[0][2], 0, 0, 0); \
            acc[0][3] = __builtin_amdgcn_mfma_f32_16x16x32_fp8_fp8((long)a0v.y, (long)b3v.y, acc[0][3], 0, 0, 0); \
            acc[1][0] = __builtin_amdgcn_mfma_f32_16x16x32_fp8_fp8((long)a1v.y, (long)b0v.y, acc[1][0], 0, 0, 0); \
            acc[1][1] = __builtin_amdgcn_mfma_f32_16x16x32_fp8_fp8((long)a1v.y, (long)b1v.y, acc[1][1], 0, 0, 0); \
            acc[1][2] = __builtin_amdgcn_mfma_f32_16x16x32_fp8_fp8((long)a1v.y, (long)b2v.y, acc[1][2], 0, 0, 0); \
            acc[1][3] = __builtin_amdgcn_mfma_f32_16x16x32_fp8_fp8((long)a1v.y, (long)b3v.y, acc[1][3], 0, 0, 0); \
        }                                                                        \
    }

    LOADC3(A, 0);
    LOADC3(B, 1);
    int kc = 0;
    for (; kc + 2 <= 3; kc += 2) {
        if (kc) __syncthreads();
        STAGE3(A, kc);
        if (kc + 2 < 3) LOADC3(A, kc + 2);
        __syncthreads();
        MFMA_STEP3;
        __syncthreads();
        STAGE3(B, kc + 1);
        __syncthreads();
        MFMA_STEP3;
    }
    {   // tail chunk 2 (set A)
        __syncthreads();
        STAGE3(A, 2);
        __syncthreads();
        MFMA_STEP3;
    }
#undef LOADC3
#undef STAGE3
#undef MFMA_STEP3

    __syncthreads();                 // all LDS readers done before red overlay
    float lsum = 0.f, lsq = 0.f;
#pragma unroll
    for (int i = 0; i < 2; i++) {
        const int ob = wo * 32 + i * 16 + quad * 4;
        const float4 bv = *(const float4*)(bias + ob);
        float mx0 = -1e30f, mx1 = -1e30f, mx2 = -1e30f, mx3 = -1e30f;
#pragma unroll
        for (int t = 0; t < 4; t++) {
            const int n = nt0 + wn * 64 + t * 16 + l15;
            float v0 = acc[i][t][0] + bv.x;
            float v1 = acc[i][t][1] + bv.y;
            float v2 = acc[i][t][2] + bv.z;
            float v3 = acc[i][t][3] + bv.w;
            if (n == 0) { v0 = v1 = v2 = v3 = 0.f; }
            lsum += v0 + v1 + v2 + v3;
            lsq  += v0 * v0 + v1 * v1 + v2 * v2 + v3 * v3;
            mx0 = fmaxf(mx0, v0); mx1 = fmaxf(mx1, v1);
            mx2 = fmaxf(mx2, v2); mx3 = fmaxf(mx3, v3);
        }
#pragma unroll
        for (int off = 1; off < 16; off <<= 1) {
            mx0 = fmaxf(mx0, __shfl_xor(mx0, off));
            mx1 = fmaxf(mx1, __shfl_xor(mx1, off));
            mx2 = fmaxf(mx2, __shfl_xor(mx2, off));
            mx3 = fmaxf(mx3, __shfl_xor(mx3, off));
        }
        if (l15 == 0) {
            atomicMaxF(&pmax[(size_t)b * 64 + ob + 0], mx0);
            atomicMaxF(&pmax[(size_t)b * 64 + ob + 1], mx1);
            atomicMaxF(&pmax[(size_t)b * 64 + ob + 2], mx2);
            atomicMaxF(&pmax[(size_t)b * 64 + ob + 3], mx3);
        }
    }
#pragma unroll
    for (int off = 32; off > 0; off >>= 1) {
        lsum += __shfl_down(lsum, off);
        lsq  += __shfl_down(lsq, off);
    }
    float* red = (float*)wt8;
    if (lane == 0) { red[wave] = lsum; red[8 + wave] = lsq; }
    __syncthreads();
    if (tid == 0) {
        float a0 = 0.f, a1v = 0.f;
#pragma unroll
        for (int w = 0; w < 8; ++w) { a0 += red[w]; a1v += red[8 + w]; }
        atomicAdd(&sums[2 * b + 0], a0);
        atomicAdd(&sums[2 * b + 1], a1v);
    }
}

// pooled max -> normalize -> fc1+lrelu -> fc2
__global__ __launch_bounds__(64) void fc_head(
    const float* __restrict__ pmax, const float* __restrict__ sums3, float count,
    const float* __restrict__ w_fc1, const float* __restrict__ b_fc1,
    const float* __restrict__ w_fc2, const float* __restrict__ b_fc2,
    float* __restrict__ y)
{
    const int b = blockIdx.x, t = threadIdx.x;
    __shared__ float pooled[64];
    __shared__ float hid[32];
    float2 s = stats_from(sums3, b, count);
    pooled[t] = (pmax[(size_t)b * 64 + t] - s.x) * s.y;
    __syncthreads();
    if (t < 32) {
        float h = b_fc1[t];
#pragma unroll
        for (int c = 0; c < 64; c++) h += pooled[c] * w_fc1[t * 64 + c];
        hid[t] = LRELU(h);
    }
    __syncthreads();
    if (t == 0) {
        float v = b_fc2[0];
#pragma unroll
        for (int c = 0; c < 32; c++) v += hid[c] * w_fc2[c];
        y[b] = v;
    }
}

__global__ void sigmoid_diff(const float* __restrict__ y1,
                             const float* __restrict__ y2,
                             float* __restrict__ out)
{
    int b = threadIdx.x;
    if (b < 128) out[b] = 1.0f / (1.0f + expf(-(y1[b] - y2[b])));
}

extern "C" void kernel_launch(void* const* d_in, const int* in_sizes, int n_in,
                              void* d_out, int out_size, void* d_ws, size_t ws_size,
                              hipStream_t stream)
{
    const float* data1 = (const float*)d_in[0];
    const int*   idx1  = (const int*)d_in[1];
    const float* data2 = (const float*)d_in[2];
    const int*   idx2  = (const int*)d_in[3];
    const float* w1 = (const float*)d_in[4];
    const float* b1 = (const float*)d_in[5];
    const float* w2 = (const float*)d_in[6];
    const float* b2 = (const float*)d_in[7];
    const float* w3 = (const float*)d_in[8];
    const float* b3 = (const float*)d_in[9];
    const float* wfc1 = (const float*)d_in[10];
    const float* bfc1 = (const float*)d_in[11];
    const float* wfc2 = (const float*)d_in[12];
    const float* bfc2 = (const float*)d_in[13];

    // a1 and a2 are fp8 (1B/elem); xT stays bf16
    const size_t needM = (size_t)256 * 1024 * (64 * 2 + 256 * 1 + 128 * 1) + 768 * 1024;
    const bool merged = ws_size >= needM;
    const int nB = merged ? 256 : 128;
    const size_t szXT = (size_t)nB * 1024 * 64 * 2;
    const size_t szA1 = (size_t)nB * 1024 * 256;       // fp8
    const size_t szA2 = (size_t)nB * 1024 * 128;       // fp8

    char* ws = (char*)d_ws;
    unsigned short* xT = (unsigned short*)ws;
    unsigned char*  a1 = (unsigned char*)(ws + szXT);
    unsigned char*  a2 = (unsigned char*)(ws + szXT + szA1);
    char* tail = ws + szXT + szA1 + szA2;
    unsigned short* wq1   = (unsigned short*)tail;               // 96 KB
    unsigned char*  wq2f8 = (unsigned char*)(tail + 128 * 1024); // 96 KB (fp8)
    unsigned char*  wq3f8 = (unsigned char*)(tail + 384 * 1024); // 24 KB (fp8)
    float* sums = (float*)(tail + 448 * 1024);                   // 3*nB*2 f32
    float* pmax = (float*)(tail + 512 * 1024);                   // nB*64 f32
    float* yv   = (float*)(tail + 640 * 1024);                   // 256 f32

    prep_all<<<96, 256, 0, stream>>>(w1, wq1, w2, wq2f8, w3, wq3f8);

    const int nIter = merged ? 1 : 2;
    for (int t = 0; t < nIter; ++t) {
        const float* dA = (merged || t == 0) ? data1 : data2;
        const float* dB = merged ? data2 : dA;
        const int* iA = (merged || t == 0) ? idx1 : idx2;
        const int* iB = merged ? idx2 : iA;
        float* s1 = sums;
        float* s2 = sums + nB * 2;
        float* s3 = sums + nB * 4;

        // sums/pmax re-init folded into transpose_in block (0,0)
        transpose_in<<<dim3(16, nB), 256, 0, stream>>>(dA, dB, xT, sums,
                                                       (unsigned int*)pmax);

        conv1_mfma<<<dim3(nB, 1, 8), 512, 0, stream>>>(
            xT, iA, iB, wq1, b1, a1, s1);

        norm_act_fp8<<<dim3(16, nB), 256, 0, stream>>>(a1, s1, 256.0f * 1024.0f, 16384);

        conv2_fp8<<<dim3(nB, 1, 4), 512, 0, stream>>>(
            a1, iA, iB, wq2f8, b2, a2, s2);

        norm_act_fp8<<<dim3(8, nB), 256, 0, stream>>>(a2, s2, 128.0f * 1024.0f, 8192);

        conv3_fp8<<<dim3(nB, 1, 4), 512, 0, stream>>>(
            a2, iA, iB, wq3f8, b3, s3, pmax);

        fc_head<<<nB, 64, 0, stream>>>(pmax, s3, 64.0f * 1024.0f,
                                       wfc1, bfc1, wfc2, bfc2,
                                       yv + (merged ? 0 : t * 128));
    }
    sigmoid_diff<<<1, 128, 0, stream>>>(yv, yv + 128, (float*)d_out);
}

// Round 7
// 263.663 us; speedup vs baseline: 1.1702x; 1.1702x over previous
//
#include <hip/hip_runtime.h>
#include <math.h>

typedef __attribute__((ext_vector_type(4))) float f32x4;
typedef __attribute__((ext_vector_type(2))) float f32x2;

#define LRELU(x) ((x) > 0.0f ? (x) : 0.01f * (x))

struct __align__(4) Int3 { int x, y, z; };

__device__ __forceinline__ float2 stats_from(const float* sums, int b, float count) {
    float s = sums[2 * b], q = sums[2 * b + 1];
    float mean = s / count;
    float var = (q - s * s / count) / (count - 1.0f);  // ddof=1
    var = fmaxf(var, 0.0f);
    return make_float2(mean, 1.0f / (sqrtf(var) + 1e-5f));
}
// init pattern 0xFFFFFFFF (-NaN): positives via signed max, negatives via unsigned min
__device__ __forceinline__ void atomicMaxF(float* a, float v) {
    if (v >= 0.0f) atomicMax((int*)a, __float_as_int(v));
    else           atomicMin((unsigned int*)a, __float_as_uint(v));
}
// 4 fp8 e4m3 -> lrelu(x*a+c) -> 4 fp8 e4m3 (in-register, for the norm_act passes)
__device__ __forceinline__ unsigned int fp8x4_nact(unsigned int u, float a, float c) {
    f32x2 lo = __builtin_amdgcn_cvt_pk_f32_fp8(u, false);
    f32x2 hi = __builtin_amdgcn_cvt_pk_f32_fp8(u, true);
    lo = lo * a + c; hi = hi * a + c;
    f32x2 ml = lo * 0.01f, mh = hi * 0.01f;
    lo = __builtin_elementwise_max(lo, ml);
    hi = __builtin_elementwise_max(hi, mh);
    int r = __builtin_amdgcn_cvt_pk_fp8_f32(lo.x, lo.y, 0, false);
    r = __builtin_amdgcn_cvt_pk_fp8_f32(hi.x, hi.y, r, true);
    return (unsigned int)r;
}
// R15 k-byte permutation within each 128-byte chunk: fp8 fragment pairs land on
// one contiguous 16B column -> ds_read_b128, bf16-identical 0-conflict geometry.
__device__ __forceinline__ int perm128(int o) {
    return ((o >> 6) << 6) | (((o >> 3) & 3) << 4) | (((o >> 5) & 1) << 3) | (o & 7);
}
// R17 analog for 64-byte chunks (conv1: Cin=64): byte position p holds channel
// k(p) = 32*((p>>3)&1) + 8*(p>>4) + (p&7), so 16B col q = {stage0,stage1} frags
// of quad q. Applied at producers (transpose_in, prep w1).

// w1 -> fp8 [256][192] perm64; w2 -> fp8 [128][768] perm128; w3 -> fp8 [64][384] perm128
__global__ void prep_all(const float* __restrict__ w1, unsigned char* __restrict__ wq1,
                         const float* __restrict__ w2, unsigned char* __restrict__ wq2,
                         const float* __restrict__ w3, unsigned char* __restrict__ wq3)
{
    const int tid = blockIdx.x * blockDim.x + threadIdx.x;
    const int stride = gridDim.x * blockDim.x;
    // w1: dest byte r0 within row -> chunk kc (j), perm64 pos -> channel
    for (int i = tid; i < (256 * 192) >> 2; i += stride) {
        const int e0 = i << 2;
        const int o = e0 / 192, r0 = e0 - o * 192;
        const int kc = r0 >> 6, p0 = r0 & 63;
        const int k0 = (((p0 >> 3) & 1) << 5) + ((p0 >> 4) << 3) + (p0 & 7);
        const float* src = &w1[(o * 64 + k0) * 3 + kc];
        float f0 = src[0], f1 = src[3], f2 = src[6], f3 = src[9];
        int r = __builtin_amdgcn_cvt_pk_fp8_f32(f0, f1, 0, false);
        r = __builtin_amdgcn_cvt_pk_fp8_f32(f2, f3, r, true);
        *(unsigned int*)&wq1[e0] = (unsigned int)r;
    }
    for (int i = tid; i < (128 * 768) >> 2; i += stride) {
        const int e0 = i << 2;
        const int o = e0 / 768, r0 = e0 - o * 768;
        const int kc = r0 >> 7, ro = r0 & 127;
        const int k0 = ((ro >> 6) << 6) + (((ro >> 3) & 1) << 5) + (((ro >> 4) & 3) << 3) + (ro & 7);
        const int kp0 = kc * 128 + k0;
        const int j = kp0 >> 8, c0 = kp0 & 255;
        const float* src = &w2[(o * 256 + c0) * 3 + j];
        float f0 = src[0], f1 = src[3], f2 = src[6], f3 = src[9];
        int r = __builtin_amdgcn_cvt_pk_fp8_f32(f0, f1, 0, false);
        r = __builtin_amdgcn_cvt_pk_fp8_f32(f2, f3, r, true);
        *(unsigned int*)&wq2[e0] = (unsigned int)r;
    }
    for (int i = tid; i < (64 * 384) >> 2; i += stride) {
        const int e0 = i << 2;
        const int o = e0 / 384, r0 = e0 - o * 384;
        const int kc = r0 >> 7, ro = r0 & 127;
        const int k0 = ((ro >> 6) << 6) + (((ro >> 3) & 1) << 5) + (((ro >> 4) & 3) << 3) + (ro & 7);
        const int kp0 = kc * 128 + k0;
        const int j = kp0 >> 7, c0 = kp0 & 127;
        const float* src = &w3[(o * 128 + c0) * 3 + j];
        float f0 = src[0], f1 = src[3], f2 = src[6], f3 = src[9];
        int r = __builtin_amdgcn_cvt_pk_fp8_f32(f0, f1, 0, false);
        r = __builtin_amdgcn_cvt_pk_fp8_f32(f2, f3, r, true);
        *(unsigned int*)&wq3[e0] = (unsigned int)r;
    }
}

// R17: data [128][64][1024] f32 -> xT [nB][1024][64] FP8 e4m3, perm64 rows.
// Halves conv1's gather bytes/requests and this kernel's streaming write.
// block (0,0) also re-inits sums/pmax (replaces 2 hipMemsetAsync dispatches)
__global__ __launch_bounds__(256) void transpose_in(const float* __restrict__ inA,
                                                    const float* __restrict__ inB,
                                                    unsigned char* __restrict__ xT8,
                                                    float* __restrict__ sums,
                                                    unsigned int* __restrict__ pmax)
{
    const int b = blockIdx.y, n0 = blockIdx.x * 64;
    const float* in = (b >= 128 ? inB : inA) + ((size_t)(b & 127) * 64) * 1024;
    const int tid = threadIdx.x;
    if (blockIdx.x == 0 && blockIdx.y == 0) {
        const int nBv = gridDim.y;
        for (int i = tid; i < 3 * nBv * 2; i += 256) sums[i] = 0.0f;
        for (int i = tid; i < nBv * 64; i += 256) pmax[i] = 0xFFFFFFFFu;
    }
    __shared__ float tile[64][65];
    const int nn = tid & 63, cw = tid >> 6;
#pragma unroll
    for (int i = 0; i < 16; i++) {
        int c = i * 4 + cw;
        tile[c][nn] = in[(size_t)c * 1024 + n0 + nn];
    }
    __syncthreads();
    const int n = tid >> 2, cg = tid & 3;   // dst bytes cg*16..+15
    unsigned int u0, u1, u2, u3;
    {   // word w: channels k = ((w>>1)<<5) + cg*8 + ((w&1)<<2) + 0..3
        int k0 = cg * 8;
        float f0 = tile[k0][n], f1 = tile[k0 + 1][n], f2 = tile[k0 + 2][n], f3 = tile[k0 + 3][n];
        int r = __builtin_amdgcn_cvt_pk_fp8_f32(f0, f1, 0, false);
        u0 = (unsigned int)__builtin_amdgcn_cvt_pk_fp8_f32(f2, f3, r, true);
    }
    {
        int k0 = cg * 8 + 4;
        float f0 = tile[k0][n], f1 = tile[k0 + 1][n], f2 = tile[k0 + 2][n], f3 = tile[k0 + 3][n];
        int r = __builtin_amdgcn_cvt_pk_fp8_f32(f0, f1, 0, false);
        u1 = (unsigned int)__builtin_amdgcn_cvt_pk_fp8_f32(f2, f3, r, true);
    }
    {
        int k0 = 32 + cg * 8;
        float f0 = tile[k0][n], f1 = tile[k0 + 1][n], f2 = tile[k0 + 2][n], f3 = tile[k0 + 3][n];
        int r = __builtin_amdgcn_cvt_pk_fp8_f32(f0, f1, 0, false);
        u2 = (unsigned int)__builtin_amdgcn_cvt_pk_fp8_f32(f2, f3, r, true);
    }
    {
        int k0 = 32 + cg * 8 + 4;
        float f0 = tile[k0][n], f1 = tile[k0 + 1][n], f2 = tile[k0 + 2][n], f3 = tile[k0 + 3][n];
        int r = __builtin_amdgcn_cvt_pk_fp8_f32(f0, f1, 0, false);
        u3 = (unsigned int)__builtin_amdgcn_cvt_pk_fp8_f32(f2, f3, r, true);
    }
    unsigned char* dst = xT8 + ((size_t)b * 1024 + n0 + n) * 64 + cg * 16;
    uint4 v = {u0, u1, u2, u3};
    *(uint4*)dst = v;
}

// apply lrelu(norm(.)) ONCE per element (in place). u4PerB = uint4s per batch row.
__global__ __launch_bounds__(256) void norm_act_fp8(unsigned char* __restrict__ a,
                                                    const float* __restrict__ sums,
                                                    float count, int u4PerB)
{
    const int b = blockIdx.y;
    float2 st = stats_from(sums, b, count);
    const float na = st.y, nc = -st.x * st.y;
    uint4* p = (uint4*)a + (size_t)b * u4PerB;
    for (int idx = blockIdx.x * 256 + threadIdx.x; idx < u4PerB; idx += gridDim.x * 256) {
        uint4 v = p[idx];
        v.x = fp8x4_nact(v.x, na, nc);
        v.y = fp8x4_nact(v.y, na, nc);
        v.z = fp8x4_nact(v.z, na, nc);
        v.w = fp8x4_nact(v.w, na, nc);
        p[idx] = v;
    }
}

// R17: conv1 as fp8 x fp8 MFMA, cloned from the PROVEN conv2_fp8 geometry
// (128-row x 128B LDS tiles, XOR-by-row&7 16B-col swizzle, b128 paired frag
// reads). K=192 = 2 fills: {chunks 0,1} then {chunk 2, half-staged}. Grid and
// __launch_bounds__(256,3) exactly as R15 (R16 taught: 3 blocks/CU is load-
// bearing; 512-thr/1-block regressed 52->71us). K-loop vmem requests halved.
__global__ __launch_bounds__(256, 3) void conv1_fp8(
    const unsigned char* __restrict__ xT8,   // [nB][1024][64] fp8, perm64 rows
    const int* __restrict__ idxA,            // [128][3069]
    const int* __restrict__ idxB,
    const unsigned char* __restrict__ wq8,   // [256][192] fp8, perm64 chunks
    const float* __restrict__ bias,          // [256] f32
    unsigned char* __restrict__ out,         // [nB][1024][256] fp8 (perm128 channels)
    float* __restrict__ sums)                // [nB][2]
{
    const int b   = blockIdx.x;
    const int o0  = blockIdx.y * 128;
    const int nt0 = blockIdx.z << 7;
    const int tid = threadIdx.x;
    const int lane = tid & 63, wave = tid >> 6;
    const int wo = wave & 1, wn = wave >> 1;
    const int quad = lane >> 4, l15 = lane & 15;
    const int blkid = lane & 7;

    __shared__ __align__(16) unsigned char wt8[128 * 128];
    __shared__ __align__(16) unsigned char gt8[128 * 128];

    f32x4 acc[4][4];
#pragma unroll
    for (int i = 0; i < 4; i++)
#pragma unroll
        for (int t = 0; t < 4; t++) acc[i][t] = (f32x4){0.f, 0.f, 0.f, 0.f};

    const unsigned char* xb = xT8 + (((size_t)b) << 10) * 64;
    const int* idxb = (b >= 128 ? idxB : idxA) + (size_t)(b & 127) * 3069;

    const int gr = tid >> 1, gh = tid & 1;   // row (n and o coincide); chunk-in-fill
    int s0, s1, s2;
    {
        int n = nt0 + gr;
        int t0 = (n == 0) ? 0 : (n - 1);     // n==0 row garbage, zeroed in epilogue
        const Int3 sv = *(const Int3*)&idxb[3 * t0];
        s0 = sv.x; s1 = sv.y; s2 = sv.z;
    }
    const unsigned char* wrow = wq8 + (size_t)(o0 + gr) * 192;
    const int swz = gr & 7;

    uint4 g0A, g1A, g2A, g3A, w0A, w1A, w2A, w3A;
    uint4 g0B, g1B, g2B, g3B, w0B, w1B, w2B, w3B;

    // fill0 loads: thread gh owns chunk gh (full 64B source row / weight chunk)
    {
        const int srcA = gh ? s1 : s0;
        const uint4* gp = (const uint4*)(xb + (size_t)srcA * 64);
        g0A = gp[0]; g1A = gp[1]; g2A = gp[2]; g3A = gp[3];
        const uint4* wp = (const uint4*)(wrow + (gh << 6));
        w0A = wp[0]; w1A = wp[1]; w2A = wp[2]; w3A = wp[3];
    }
    // fill1 loads (chunk 2): gh==0 lanes only
    if (gh == 0) {
        const uint4* gp = (const uint4*)(xb + (size_t)s2 * 64);
        g0B = gp[0]; g1B = gp[1]; g2B = gp[2]; g3B = gp[3];
        const uint4* wp = (const uint4*)(wrow + 128);
        w0B = wp[0]; w1B = wp[1]; w2B = wp[2]; w3B = wp[3];
    }

    // STAGE fill0: logical col = chunk*4 + q, physical = logical ^ (row&7)
    *(uint4*)&gt8[gr * 128 + (((gh << 2) | 0) ^ swz) * 16] = g0A;
    *(uint4*)&gt8[gr * 128 + (((gh << 2) | 1) ^ swz) * 16] = g1A;
    *(uint4*)&gt8[gr * 128 + (((gh << 2) | 2) ^ swz) * 16] = g2A;
    *(uint4*)&gt8[gr * 128 + (((gh << 2) | 3) ^ swz) * 16] = g3A;
    *(uint4*)&wt8[gr * 128 + (((gh << 2) | 0) ^ swz) * 16] = w0A;
    *(uint4*)&wt8[gr * 128 + (((gh << 2) | 1) ^ swz) * 16] = w1A;
    *(uint4*)&wt8[gr * 128 + (((gh << 2) | 2) ^ swz) * 16] = w2A;
    *(uint4*)&wt8[gr * 128 + (((gh << 2) | 3) ^ swz) * 16] = w3A;

#define MFMA_PP(PP) {                                                            \
        ulonglong2 a0v, a1v, a2v, a3v, b0v, b1v, b2v, b3v;                       \
        {                                                                        \
            const int cx = ((((PP) * 4 + quad) ^ blkid) << 4);                   \
            a0v = *(const ulonglong2*)&wt8[(wo * 64 +  0 + l15) * 128 + cx];     \
            a1v = *(const ulonglong2*)&wt8[(wo * 64 + 16 + l15) * 128 + cx];     \
            a2v = *(const ulonglong2*)&wt8[(wo * 64 + 32 + l15) * 128 + cx];     \
            a3v = *(const ulonglong2*)&wt8[(wo * 64 + 48 + l15) * 128 + cx];     \
            b0v = *(const ulonglong2*)&gt8[(wn * 64 +  0 + l15) * 128 + cx];     \
            b1v = *(const ulonglong2*)&gt8[(wn * 64 + 16 + l15) * 128 + cx];     \
            b2v = *(const ulonglong2*)&gt8[(wn * 64 + 32 + l15) * 128 + cx];     \
            b3v = *(const ulonglong2*)&gt8[(wn * 64 + 48 + l15) * 128 + cx];     \
        }                                                                        \
        acc[0][0] = __builtin_amdgcn_mfma_f32_16x16x32_fp8_fp8((long)a0v.x, (long)b0v.x, acc[0][0], 0, 0, 0); \
        acc[0][1] = __builtin_amdgcn_mfma_f32_16x16x32_fp8_fp8((long)a0v.x, (long)b1v.x, acc[0][1], 0, 0, 0); \
        acc[0][2] = __builtin_amdgcn_mfma_f32_16x16x32_fp8_fp8((long)a0v.x, (long)b2v.x, acc[0][2], 0, 0, 0); \
        acc[0][3] = __builtin_amdgcn_mfma_f32_16x16x32_fp8_fp8((long)a0v.x, (long)b3v.x, acc[0][3], 0, 0, 0); \
        acc[1][0] = __builtin_amdgcn_mfma_f32_16x16x32_fp8_fp8((long)a1v.x, (long)b0v.x, acc[1][0], 0, 0, 0); \
        acc[1][1] = __builtin_amdgcn_mfma_f32_16x16x32_fp8_fp8((long)a1v.x, (long)b1v.x, acc[1][1], 0, 0, 0); \
        acc[1][2] = __builtin_amdgcn_mfma_f32_16x16x32_fp8_fp8((long)a1v.x, (long)b2v.x, acc[1][2], 0, 0, 0); \
        acc[1][3] = __builtin_amdgcn_mfma_f32_16x16x32_fp8_fp8((long)a1v.x, (long)b3v.x, acc[1][3], 0, 0, 0); \
        acc[2][0] = __builtin_amdgcn_mfma_f32_16x16x32_fp8_fp8((long)a2v.x, (long)b0v.x, acc[2][0], 0, 0, 0); \
        acc[2][1] = __builtin_amdgcn_mfma_f32_16x16x32_fp8_fp8((long)a2v.x, (long)b1v.x, acc[2][1], 0, 0, 0); \
        acc[2][2] = __builtin_amdgcn_mfma_f32_16x16x32_fp8_fp8((long)a2v.x, (long)b2v.x, acc[2][2], 0, 0, 0); \
        acc[2][3] = __builtin_amdgcn_mfma_f32_16x16x32_fp8_fp8((long)a2v.x, (long)b3v.x, acc[2][3], 0, 0, 0); \
        acc[3][0] = __builtin_amdgcn_mfma_f32_16x16x32_fp8_fp8((long)a3v.x, (long)b0v.x, acc[3][0], 0, 0, 0); \
        acc[3][1] = __builtin_amdgcn_mfma_f32_16x16x32_fp8_fp8((long)a3v.x, (long)b1v.x, acc[3][1], 0, 0, 0); \
        acc[3][2] = __builtin_amdgcn_mfma_f32_16x16x32_fp8_fp8((long)a3v.x, (long)b2v.x, acc[3][2], 0, 0, 0); \
        acc[3][3] = __builtin_amdgcn_mfma_f32_16x16x32_fp8_fp8((long)a3v.x, (long)b3v.x, acc[3][3], 0, 0, 0); \
        acc[0][0] = __builtin_amdgcn_mfma_f32_16x16x32_fp8_fp8((long)a0v.y, (long)b0v.y, acc[0][0], 0, 0, 0); \
        acc[0][1] = __builtin_amdgcn_mfma_f32_16x16x32_fp8_fp8((long)a0v.y, (long)b1v.y, acc[0][1], 0, 0, 0); \
        acc[0][2] = __builtin_amdgcn_mfma_f32_16x16x32_fp8_fp8((long)a0v.y, (long)b2v.y, acc[0][2], 0, 0, 0); \
        acc[0][3] = __builtin_amdgcn_mfma_f32_16x16x32_fp8_fp8((long)a0v.y, (long)b3v.y, acc[0][3], 0, 0, 0); \
        acc[1][0] = __builtin_amdgcn_mfma_f32_16x16x32_fp8_fp8((long)a1v.y, (long)b0v.y, acc[1][0], 0, 0, 0); \
        acc[1][1] = __builtin_amdgcn_mfma_f32_16x16x32_fp8_fp8((long)a1v.y, (long)b1v.y, acc[1][1], 0, 0, 0); \
        acc[1][2] = __builtin_amdgcn_mfma_f32_16x16x32_fp8_fp8((long)a1v.y, (long)b2v.y, acc[1][2], 0, 0, 0); \
        acc[1][3] = __builtin_amdgcn_mfma_f32_16x16x32_fp8_fp8((long)a1v.y, (long)b3v.y, acc[1][3], 0, 0, 0); \
        acc[2][0] = __builtin_amdgcn_mfma_f32_16x16x32_fp8_fp8((long)a2v.y, (long)b0v.y, acc[2][0], 0, 0, 0); \
        acc[2][1] = __builtin_amdgcn_mfma_f32_16x16x32_fp8_fp8((long)a2v.y, (long)b1v.y, acc[2][1], 0, 0, 0); \
        acc[2][2] = __builtin_amdgcn_mfma_f32_16x16x32_fp8_fp8((long)a2v.y, (long)b2v.y, acc[2][2], 0, 0, 0); \
        acc[2][3] = __builtin_amdgcn_mfma_f32_16x16x32_fp8_fp8((long)a2v.y, (long)b3v.y, acc[2][3], 0, 0, 0); \
        acc[3][0] = __builtin_amdgcn_mfma_f32_16x16x32_fp8_fp8((long)a3v.y, (long)b0v.y, acc[3][0], 0, 0, 0); \
        acc[3][1] = __builtin_amdgcn_mfma_f32_16x16x32_fp8_fp8((long)a3v.y, (long)b1v.y, acc[3][1], 0, 0, 0); \
        acc[3][2] = __builtin_amdgcn_mfma_f32_16x16x32_fp8_fp8((long)a3v.y, (long)b2v.y, acc[3][2], 0, 0, 0); \
        acc[3][3] = __builtin_amdgcn_mfma_f32_16x16x32_fp8_fp8((long)a3v.y, (long)b3v.y, acc[3][3], 0, 0, 0); \
    }

    __syncthreads();
    MFMA_PP(0);
    MFMA_PP(1);
    __syncthreads();
    // STAGE fill1 (chunk 2 -> logical cols 0..3); gh==1 lanes idle
    if (gh == 0) {
        *(uint4*)&gt8[gr * 128 + ((0 ^ swz) * 16)] = g0B;
        *(uint4*)&gt8[gr * 128 + ((1 ^ swz) * 16)] = g1B;
        *(uint4*)&gt8[gr * 128 + ((2 ^ swz) * 16)] = g2B;
        *(uint4*)&gt8[gr * 128 + ((3 ^ swz) * 16)] = g3B;
        *(uint4*)&wt8[gr * 128 + ((0 ^ swz) * 16)] = w0B;
        *(uint4*)&wt8[gr * 128 + ((1 ^ swz) * 16)] = w1B;
        *(uint4*)&wt8[gr * 128 + ((2 ^ swz) * 16)] = w2B;
        *(uint4*)&wt8[gr * 128 + ((3 ^ swz) * 16)] = w3B;
    }
    __syncthreads();
    MFMA_PP(0);
#undef MFMA_PP

    __syncthreads();                 // all LDS readers done
    unsigned char* eb = gt8;         // [128 n][128 o'] fp8, bank-swizzled
    float lsum = 0.f, lsq = 0.f;
#pragma unroll
    for (int i = 0; i < 4; i++) {
        const int obl = wo * 64 + i * 16 + quad * 4;
        const int op  = perm128(obl);         // channel remap for a1 (conv2's layout)
        const float4 bv = *(const float4*)(bias + o0 + obl);
#pragma unroll
        for (int t = 0; t < 4; t++) {
            const int nl = wn * 64 + t * 16 + l15;
            float v0 = acc[i][t][0] + bv.x;
            float v1 = acc[i][t][1] + bv.y;
            float v2 = acc[i][t][2] + bv.z;
            float v3 = acc[i][t][3] + bv.w;
            if (nt0 + nl == 0) { v0 = v1 = v2 = v3 = 0.f; }
            lsum += v0 + v1 + v2 + v3;
            lsq  += v0 * v0 + v1 * v1 + v2 * v2 + v3 * v3;
            int r = __builtin_amdgcn_cvt_pk_fp8_f32(v0, v1, 0, false);
            r = __builtin_amdgcn_cvt_pk_fp8_f32(v2, v3, r, true);
            *(unsigned int*)&eb[nl * 128 + (op ^ ((nl & 7) << 4))] = (unsigned int)r;
        }
    }
#pragma unroll
    for (int off = 32; off > 0; off >>= 1) {
        lsum += __shfl_down(lsum, off);
        lsq  += __shfl_down(lsq, off);
    }
    float* red = (float*)wt8;
    if (lane == 0) { red[wave] = lsum; red[4 + wave] = lsq; }
    __syncthreads();
    // dense store: 128 rows x 128B tile -> 16B/lane
#pragma unroll
    for (int c = 0; c < 4; ++c) {
        const int ch = c * 256 + tid;
        const int row = ch >> 3, off = (ch & 7) << 4;
        uint4 v = *(const uint4*)&eb[row * 128 + (off ^ ((row & 7) << 4))];
        *(uint4*)&out[((size_t)b * 1024 + nt0 + row) * 256 + o0 + off] = v;
    }
    if (tid == 0) {
        atomicAdd(&sums[2 * b + 0], red[0] + red[1] + red[2] + red[3]);
        atomicAdd(&sums[2 * b + 1], red[4] + red[5] + red[6] + red[7]);
    }
}

// conv2: pure-copy-stage fp8 x fp8 MFMA on k-permuted data (R15 verbatim).
__global__ __launch_bounds__(256, 3) void conv2_fp8(
    const unsigned char* __restrict__ a1,    // [nB][1024][256] fp8, normalized, permuted
    const int* __restrict__ idxA,
    const int* __restrict__ idxB,
    const unsigned char* __restrict__ wq8,   // [128][768] fp8 e4m3, k-permuted
    const float* __restrict__ bias,          // [128] f32
    unsigned char* __restrict__ out,         // [nB][1024][128] fp8 raw (permuted)
    float* __restrict__ sums)                // [nB][2]
{
    const int b   = blockIdx.x;
    const int nt0 = blockIdx.z << 7;
    const int tid = threadIdx.x;
    const int lane = tid & 63, wave = tid >> 6;
    const int wo = wave & 1, wn = wave >> 1;
    const int quad = lane >> 4, l15 = lane & 15;
    const int blkid = lane & 7;

    __shared__ __align__(16) unsigned char wt8[128 * 128];
    __shared__ __align__(16) unsigned char gt8[128 * 128];

    f32x4 acc[4][4];
#pragma unroll
    for (int i = 0; i < 4; i++)
#pragma unroll
        for (int t = 0; t < 4; t++) acc[i][t] = (f32x4){0.f, 0.f, 0.f, 0.f};

    const unsigned char* xb = a1 + (((size_t)b) << 10) * 256;
    const int* idxb = (b >= 128 ? idxB : idxA) + (size_t)(b & 127) * 3069;

    const int gr = tid >> 1, gh = tid & 1;   // row, 64B-half (same for gt and wt)
    int si0, si1, si2;
    {
        int n = nt0 + gr;
        int t0 = (n == 0) ? 0 : (n - 1);
        const Int3 sv = *(const Int3*)&idxb[3 * t0];
        si0 = sv.x; si1 = sv.y; si2 = sv.z;
    }
    const unsigned char* wrow = wq8 + (size_t)gr * 768 + gh * 64;
    const int swz = gr & 7;

    uint4 g0A, g1A, g2A, g3A;
    uint4 g0B, g1B, g2B, g3B;

#define LOADC2(S, KC) {                                                          \
        const int j_  = (KC) >> 1;                                               \
        const int c0_ = ((KC) & 1) << 7;                                         \
        const int src_ = (j_ == 0) ? si0 : ((j_ == 1) ? si1 : si2);              \
        const uint4* gp_ = (const uint4*)(xb + (size_t)src_ * 256 + c0_ + gh * 64); \
        g0##S = gp_[0]; g1##S = gp_[1]; g2##S = gp_[2]; g3##S = gp_[3];          \
    }

#define STAGE2(S, KC) {                                                          \
        const uint4* wp_ = (const uint4*)(wrow + (KC) * 128);                    \
        uint4 wv0 = wp_[0], wv1 = wp_[1], wv2 = wp_[2], wv3 = wp_[3];            \
        *(uint4*)&gt8[gr * 128 + (((gh << 2) | 0) ^ swz) * 16] = g0##S;          \
        *(uint4*)&gt8[gr * 128 + (((gh << 2) | 1) ^ swz) * 16] = g1##S;          \
        *(uint4*)&gt8[gr * 128 + (((gh << 2) | 2) ^ swz) * 16] = g2##S;          \
        *(uint4*)&gt8[gr * 128 + (((gh << 2) | 3) ^ swz) * 16] = g3##S;          \
        *(uint4*)&wt8[gr * 128 + (((gh << 2) | 0) ^ swz) * 16] = wv0;            \
        *(uint4*)&wt8[gr * 128 + (((gh << 2) | 1) ^ swz) * 16] = wv1;            \
        *(uint4*)&wt8[gr * 128 + (((gh << 2) | 2) ^ swz) * 16] = wv2;            \
        *(uint4*)&wt8[gr * 128 + (((gh << 2) | 3) ^ swz) * 16] = wv3;            \
    }

#define MFMA_STEP2 {                                                             \
        _Pragma("unroll")                                                        \
        for (int pp = 0; pp < 2; ++pp) {                                         \
            ulonglong2 a0v, a1v, a2v, a3v, b0v, b1v, b2v, b3v;                   \
            {                                                                    \
                const int cx = (((pp * 4 + quad) ^ blkid) << 4);                 \
                a0v = *(const ulonglong2*)&wt8[(wo * 64 +  0 + l15) * 128 + cx]; \
                a1v = *(const ulonglong2*)&wt8[(wo * 64 + 16 + l15) * 128 + cx]; \
                a2v = *(const ulonglong2*)&wt8[(wo * 64 + 32 + l15) * 128 + cx]; \
                a3v = *(const ulonglong2*)&wt8[(wo * 64 + 48 + l15) * 128 + cx]; \
                b0v = *(const ulonglong2*)&gt8[(wn * 64 +  0 + l15) * 128 + cx]; \
                b1v = *(const ulonglong2*)&gt8[(wn * 64 + 16 + l15) * 128 + cx]; \
                b2v = *(const ulonglong2*)&gt8[(wn * 64 + 32 + l15) * 128 + cx]; \
                b3v = *(const ulonglong2*)&gt8[(wn * 64 + 48 + l15) * 128 + cx]; \
            }                                                                    \
            acc[0][0] = __builtin_amdgcn_mfma_f32_16x16x32_fp8_fp8((long)a0v.x, (long)b0v.x, acc[0][0], 0, 0, 0); \
            acc[0][1] = __builtin_amdgcn_mfma_f32_16x16x32_fp8_fp8((long)a0v.x, (long)b1v.x, acc[0][1], 0, 0, 0); \
            acc[0][2] = __builtin_amdgcn_mfma_f32_16x16x32_fp8_fp8((long)a0v.x, (long)b2v.x, acc[0][2], 0, 0, 0); \
            acc[0][3] = __builtin_amdgcn_mfma_f32_16x16x32_fp8_fp8((long)a0v.x, (long)b3v.x, acc[0][3], 0, 0, 0); \
            acc[1][0] = __builtin_amdgcn_mfma_f32_16x16x32_fp8_fp8((long)a1v.x, (long)b0v.x, acc[1][0], 0, 0, 0); \
            acc[1][1] = __builtin_amdgcn_mfma_f32_16x16x32_fp8_fp8((long)a1v.x, (long)b1v.x, acc[1][1], 0, 0, 0); \
            acc[1][2] = __builtin_amdgcn_mfma_f32_16x16x32_fp8_fp8((long)a1v.x, (long)b2v.x, acc[1][2], 0, 0, 0); \
            acc[1][3] = __builtin_amdgcn_mfma_f32_16x16x32_fp8_fp8((long)a1v.x, (long)b3v.x, acc[1][3], 0, 0, 0); \
            acc[2][0] = __builtin_amdgcn_mfma_f32_16x16x32_fp8_fp8((long)a2v.x, (long)b0v.x, acc[2][0], 0, 0, 0); \
            acc[2][1] = __builtin_amdgcn_mfma_f32_16x16x32_fp8_fp8((long)a2v.x, (long)b1v.x, acc[2][1], 0, 0, 0); \
            acc[2][2] = __builtin_amdgcn_mfma_f32_16x16x32_fp8_fp8((long)a2v.x, (long)b2v.x, acc[2][2], 0, 0, 0); \
            acc[2][3] = __builtin_amdgcn_mfma_f32_16x16x32_fp8_fp8((long)a2v.x, (long)b3v.x, acc[2][3], 0, 0, 0); \
            acc[3][0] = __builtin_amdgcn_mfma_f32_16x16x32_fp8_fp8((long)a3v.x, (long)b0v.x, acc[3][0], 0, 0, 0); \
            acc[3][1] = __builtin_amdgcn_mfma_f32_16x16x32_fp8_fp8((long)a3v.x, (long)b1v.x, acc[3][1], 0, 0, 0); \
            acc[3][2] = __builtin_amdgcn_mfma_f32_16x16x32_fp8_fp8((long)a3v.x, (long)b2v.x, acc[3][2], 0, 0, 0); \
            acc[3][3] = __builtin_amdgcn_mfma_f32_16x16x32_fp8_fp8((long)a3v.x, (long)b3v.x, acc[3][3], 0, 0, 0); \
            acc[0][0] = __builtin_amdgcn_mfma_f32_16x16x32_fp8_fp8((long)a0v.y, (long)b0v.y, acc[0][0], 0, 0, 0); \
            acc[0][1] = __builtin_amdgcn_mfma_f32_16x16x32_fp8_fp8((long)a0v.y, (long)b1v.y, acc[0][1], 0, 0, 0); \
            acc[0][2] = __builtin_amdgcn_mfma_f32_16x16x32_fp8_fp8((long)a0v.y, (long)b2v.y, acc[0][2], 0, 0, 0); \
            acc[0][3] = __builtin_amdgcn_mfma_f32_16x16x32_fp8_fp8((long)a0v.y, (long)b3v.y, acc[0][3], 0, 0, 0); \
            acc[1][0] = __builtin_amdgcn_mfma_f32_16x16x32_fp8_fp8((long)a1v.y, (long)b0v.y, acc[1][0], 0, 0, 0); \
            acc[1][1] = __builtin_amdgcn_mfma_f32_16x16x32_fp8_fp8((long)a1v.y, (long)b1v.y, acc[1][1], 0, 0, 0); \
            acc[1][2] = __builtin_amdgcn_mfma_f32_16x16x32_fp8_fp8((long)a1v.y, (long)b2v.y, acc[1][2], 0, 0, 0); \
            acc[1][3] = __builtin_amdgcn_mfma_f32_16x16x32_fp8_fp8((long)a1v.y, (long)b3v.y, acc[1][3], 0, 0, 0); \
            acc[2][0] = __builtin_amdgcn_mfma_f32_16x16x32_fp8_fp8((long)a2v.y, (long)b0v.y, acc[2][0], 0, 0, 0); \
            acc[2][1] = __builtin_amdgcn_mfma_f32_16x16x32_fp8_fp8((long)a2v.y, (long)b1v.y, acc[2][1], 0, 0, 0); \
            acc[2][2] = __builtin_amdgcn_mfma_f32_16x16x32_fp8_fp8((long)a2v.y, (long)b2v.y, acc[2][2], 0, 0, 0); \
            acc[2][3] = __builtin_amdgcn_mfma_f32_16x16x32_fp8_fp8((long)a2v.y, (long)b3v.y, acc[2][3], 0, 0, 0); \
            acc[3][0] = __builtin_amdgcn_mfma_f32_16x16x32_fp8_fp8((long)a3v.y, (long)b0v.y, acc[3][0], 0, 0, 0); \
            acc[3][1] = __builtin_amdgcn_mfma_f32_16x16x32_fp8_fp8((long)a3v.y, (long)b1v.y, acc[3][1], 0, 0, 0); \
            acc[3][2] = __builtin_amdgcn_mfma_f32_16x16x32_fp8_fp8((long)a3v.y, (long)b2v.y, acc[3][2], 0, 0, 0); \
            acc[3][3] = __builtin_amdgcn_mfma_f32_16x16x32_fp8_fp8((long)a3v.y, (long)b3v.y, acc[3][3], 0, 0, 0); \
        }                                                                        \
    }

    LOADC2(A, 0);
    LOADC2(B, 1);
    int kc = 0;
    for (; kc + 2 <= 6; kc += 2) {
        if (kc) __syncthreads();
        STAGE2(A, kc);
        if (kc + 2 < 6) LOADC2(A, kc + 2);
        __syncthreads();
        MFMA_STEP2;
        __syncthreads();
        STAGE2(B, kc + 1);
        if (kc + 3 < 6) LOADC2(B, kc + 3);
        __syncthreads();
        MFMA_STEP2;
    }
#undef LOADC2
#undef STAGE2
#undef MFMA_STEP2

    __syncthreads();                 // all LDS readers done
    unsigned char* eb = gt8;         // [128 n][128 o'] fp8, bank-swizzled
    float lsum = 0.f, lsq = 0.f;
#pragma unroll
    for (int i = 0; i < 4; i++) {
        const int obl = wo * 64 + i * 16 + quad * 4;
        const int op  = perm128(obl);
        const float4 bv = *(const float4*)(bias + obl);
#pragma unroll
        for (int t = 0; t < 4; t++) {
            const int nl = wn * 64 + t * 16 + l15;
            float v0 = acc[i][t][0] + bv.x;
            float v1 = acc[i][t][1] + bv.y;
            float v2 = acc[i][t][2] + bv.z;
            float v3 = acc[i][t][3] + bv.w;
            if (nt0 + nl == 0) { v0 = v1 = v2 = v3 = 0.f; }
            lsum += v0 + v1 + v2 + v3;
            lsq  += v0 * v0 + v1 * v1 + v2 * v2 + v3 * v3;
            int r = __builtin_amdgcn_cvt_pk_fp8_f32(v0, v1, 0, false);
            r = __builtin_amdgcn_cvt_pk_fp8_f32(v2, v3, r, true);
            *(unsigned int*)&eb[nl * 128 + (op ^ ((nl & 7) << 4))] = (unsigned int)r;
        }
    }
#pragma unroll
    for (int off = 32; off > 0; off >>= 1) {
        lsum += __shfl_down(lsum, off);
        lsq  += __shfl_down(lsq, off);
    }
    float* red = (float*)wt8;
    if (lane == 0) { red[wave] = lsum; red[4 + wave] = lsq; }
    __syncthreads();
#pragma unroll
    for (int c = 0; c < 4; ++c) {
        const int ch = c * 256 + tid;
        const int row = ch >> 3, off = (ch & 7) << 4;
        uint4 v = *(const uint4*)&eb[row * 128 + (off ^ ((row & 7) << 4))];
        *(uint4*)&out[((size_t)b * 1024 + nt0 + row) * 128 + off] = v;
    }
    if (tid == 0) {
        atomicAdd(&sums[2 * b + 0], red[0] + red[1] + red[2] + red[3]);
        atomicAdd(&sums[2 * b + 1], red[4] + red[5] + red[6] + red[7]);
    }
}

// conv3: pure-copy fp8 x fp8 MFMA on k-permuted a2 (R15 verbatim). POOL epilogue.
__global__ __launch_bounds__(256, 3) void conv3_fp8(
    const unsigned char* __restrict__ a2,    // [nB][1024][128] fp8, normalized, permuted
    const int* __restrict__ idxA,
    const int* __restrict__ idxB,
    const unsigned char* __restrict__ wq8,   // [64][384] fp8 e4m3, k-permuted
    const float* __restrict__ bias,          // [64] f32
    float* __restrict__ sums,                // [nB][2]
    float* __restrict__ pmax)                // [nB][64]
{
    const int b   = blockIdx.x;
    const int nt0 = blockIdx.z << 7;
    const int tid = threadIdx.x;
    const int lane = tid & 63, wave = tid >> 6;
    const int wo = wave & 1, wn = wave >> 1;
    const int quad = lane >> 4, l15 = lane & 15;
    const int blkid = lane & 7;

    __shared__ __align__(16) unsigned char wt8[64 * 128];
    __shared__ __align__(16) unsigned char gt8[128 * 128];

    f32x4 acc[2][4];
#pragma unroll
    for (int i = 0; i < 2; i++)
#pragma unroll
        for (int t = 0; t < 4; t++) acc[i][t] = (f32x4){0.f, 0.f, 0.f, 0.f};

    const unsigned char* xb = a2 + (((size_t)b) << 10) * 128;
    const int* idxb = (b >= 128 ? idxB : idxA) + (size_t)(b & 127) * 3069;

    const int gr = tid >> 1, gh = tid & 1;       // gt row, 64B-half
    int si0, si1, si2;
    {
        int n = nt0 + gr;
        int t0 = (n == 0) ? 0 : (n - 1);
        const Int3 sv = *(const Int3*)&idxb[3 * t0];
        si0 = sv.x; si1 = sv.y; si2 = sv.z;
    }
    const int wr = tid >> 2, wseg = tid & 3;     // wt row (o), 32B segment
    const unsigned char* wrow = wq8 + (size_t)wr * 384 + wseg * 32;
    const int gswz = gr & 7, wswz = wr & 7;

    uint4 g0A, g1A, g2A, g3A;
    uint4 g0B, g1B, g2B, g3B;

#define LOADC3(S, KC) {                                                          \
        const int src_ = ((KC) == 0) ? si0 : (((KC) == 1) ? si1 : si2);          \
        const uint4* gp_ = (const uint4*)(xb + (size_t)src_ * 128 + gh * 64);    \
        g0##S = gp_[0]; g1##S = gp_[1]; g2##S = gp_[2]; g3##S = gp_[3];          \
    }

#define STAGE3(S, KC) {                                                          \
        const uint4* wp_ = (const uint4*)(wrow + (KC) * 128);                    \
        uint4 wv0 = wp_[0], wv1 = wp_[1];                                        \
        *(uint4*)&gt8[gr * 128 + (((gh << 2) | 0) ^ gswz) * 16] = g0##S;         \
        *(uint4*)&gt8[gr * 128 + (((gh << 2) | 1) ^ gswz) * 16] = g1##S;         \
        *(uint4*)&gt8[gr * 128 + (((gh << 2) | 2) ^ gswz) * 16] = g2##S;         \
        *(uint4*)&gt8[gr * 128 + (((gh << 2) | 3) ^ gswz) * 16] = g3##S;         \
        *(uint4*)&wt8[wr * 128 + (((wseg << 1) | 0) ^ wswz) * 16] = wv0;         \
        *(uint4*)&wt8[wr * 128 + (((wseg << 1) | 1) ^ wswz) * 16] = wv1;         \
    }

#define MFMA_STEP3 {                                                             \
        _Pragma("unroll")                                                        \
        for (int pp = 0; pp < 2; ++pp) {                                         \
            ulonglong2 a0v, a1v, b0v, b1v, b2v, b3v;                             \
            {                                                                    \
                const int cx = (((pp * 4 + quad) ^ blkid) << 4);                 \
                a0v = *(const ulonglong2*)&wt8[(wo * 32 +  0 + l15) * 128 + cx]; \
                a1v = *(const ulonglong2*)&wt8[(wo * 32 + 16 + l15) * 128 + cx]; \
                b0v = *(const ulonglong2*)&gt8[(wn * 64 +  0 + l15) * 128 + cx]; \
                b1v = *(const ulonglong2*)&gt8[(wn * 64 + 16 + l15) * 128 + cx]; \
                b2v = *(const ulonglong2*)&gt8[(wn * 64 + 32 + l15) * 128 + cx]; \
                b3v = *(const ulonglong2*)&gt8[(wn * 64 + 48 + l15) * 128 + cx]; \
            }                                                                    \
            acc[0][0] = __builtin_amdgcn_mfma_f32_16x16x32_fp8_fp8((long)a0v.x, (long)b0v.x, acc[0][0], 0, 0, 0); \
            acc[0][1] = __builtin_amdgcn_mfma_f32_16x16x32_fp8_fp8((long)a0v.x, (long)b1v.x, acc[0][1], 0, 0, 0); \
            acc[0][2] = __builtin_amdgcn_mfma_f32_16x16x32_fp8_fp8((long)a0v.x, (long)b2v.x, acc[0][2], 0, 0, 0); \
            acc[0][3] = __builtin_amdgcn_mfma_f32_16x16x32_fp8_fp8((long)a0v.x, (long)b3v.x, acc[0][3], 0, 0, 0); \
            acc[1][0] = __builtin_amdgcn_mfma_f32_16x16x32_fp8_fp8((long)a1v.x, (long)b0v.x, acc[1][0], 0, 0, 0); \
            acc[1][1] = __builtin_amdgcn_mfma_f32_16x16x32_fp8_fp8((long)a1v.x, (long)b1v.x, acc[1][1], 0, 0, 0); \
            acc[1][2] = __builtin_amdgcn_mfma_f32_16x16x32_fp8_fp8((long)a1v.x, (long)b2v.x, acc[1][2], 0, 0, 0); \
            acc[1][3] = __builtin_amdgcn_mfma_f32_16x16x32_fp8_fp8((long)a1v.x, (long)b3v.x, acc[1][3], 0, 0, 0); \
            acc[0][0] = __builtin_amdgcn_mfma_f32_16x16x32_fp8_fp8((long)a0v.y, (long)b0v.y, acc[0][0], 0, 0, 0); \
            acc[0][1] = __builtin_amdgcn_mfma_f32_16x16x32_fp8_fp8((long)a0v.y, (long)b1v.y, acc[0][1], 0, 0, 0); \
            acc[0][2] = __builtin_amdgcn_mfma_f32_16x16x32_fp8_fp8((long)a0v.y, (long)b2v.y, acc[0][2], 0, 0, 0); \
            acc[0][3] = __builtin_amdgcn_mfma_f32_16x16x32_fp8_fp8((long)a0v.y, (long)b3v.y, acc[0][3], 0, 0, 0); \
            acc[1][0] = __builtin_amdgcn_mfma_f32_16x16x32_fp8_fp8((long)a1v.y, (long)b0v.y, acc[1][0], 0, 0, 0); \
            acc[1][1] = __builtin_amdgcn_mfma_f32_16x16x32_fp8_fp8((long)a1v.y, (long)b1v.y, acc[1][1], 0, 0, 0); \
            acc[1][2] = __builtin_amdgcn_mfma_f32_16x16x32_fp8_fp8((long)a1v.y, (long)b2v.y, acc[1][2], 0, 0, 0); \
            acc[1][3] = __builtin_amdgcn_mfma_f32_16x16x32_fp8_fp8((long)a1v.y, (long)b3v.y, acc[1][3], 0, 0, 0); \
        }                                                                        \
    }

    LOADC3(A, 0);
    LOADC3(B, 1);
    int kc = 0;
    for (; kc + 2 <= 3; kc += 2) {
        if (kc) __syncthreads();
        STAGE3(A, kc);
        if (kc + 2 < 3) LOADC3(A, kc + 2);
        __syncthreads();
        MFMA_STEP3;
        __syncthreads();
        STAGE3(B, kc + 1);
        __syncthreads();
        MFMA_STEP3;
    }
    {   // tail chunk 2 (set A)
        __syncthreads();
        STAGE3(A, 2);
        __syncthreads();
        MFMA_STEP3;
    }
#undef LOADC3
#undef STAGE3
#undef MFMA_STEP3

    __syncthreads();                 // all LDS readers done before red overlay
    float lsum = 0.f, lsq = 0.f;
#pragma unroll
    for (int i = 0; i < 2; i++) {
        const int ob = wo * 32 + i * 16 + quad * 4;
        const float4 bv = *(const float4*)(bias + ob);
        float mx0 = -1e30f, mx1 = -1e30f, mx2 = -1e30f, mx3 = -1e30f;
#pragma unroll
        for (int t = 0; t < 4; t++) {
            const int n = nt0 + wn * 64 + t * 16 + l15;
            float v0 = acc[i][t][0] + bv.x;
            float v1 = acc[i][t][1] + bv.y;
            float v2 = acc[i][t][2] + bv.z;
            float v3 = acc[i][t][3] + bv.w;
            if (n == 0) { v0 = v1 = v2 = v3 = 0.f; }
            lsum += v0 + v1 + v2 + v3;
            lsq  += v0 * v0 + v1 * v1 + v2 * v2 + v3 * v3;
            mx0 = fmaxf(mx0, v0); mx1 = fmaxf(mx1, v1);
            mx2 = fmaxf(mx2, v2); mx3 = fmaxf(mx3, v3);
        }
#pragma unroll
        for (int off = 1; off < 16; off <<= 1) {
            mx0 = fmaxf(mx0, __shfl_xor(mx0, off));
            mx1 = fmaxf(mx1, __shfl_xor(mx1, off));
            mx2 = fmaxf(mx2, __shfl_xor(mx2, off));
            mx3 = fmaxf(mx3, __shfl_xor(mx3, off));
        }
        if (l15 == 0) {
            atomicMaxF(&pmax[(size_t)b * 64 + ob + 0], mx0);
            atomicMaxF(&pmax[(size_t)b * 64 + ob + 1], mx1);
            atomicMaxF(&pmax[(size_t)b * 64 + ob + 2], mx2);
            atomicMaxF(&pmax[(size_t)b * 64 + ob + 3], mx3);
        }
    }
#pragma unroll
    for (int off = 32; off > 0; off >>= 1) {
        lsum += __shfl_down(lsum, off);
        lsq  += __shfl_down(lsq, off);
    }
    float* red = (float*)wt8;
    if (lane == 0) { red[wave] = lsum; red[4 + wave] = lsq; }
    __syncthreads();
    if (tid == 0) {
        atomicAdd(&sums[2 * b + 0], red[0] + red[1] + red[2] + red[3]);
        atomicAdd(&sums[2 * b + 1], red[4] + red[5] + red[6] + red[7]);
    }
}

// pooled max -> normalize -> fc1+lrelu -> fc2
__global__ __launch_bounds__(64) void fc_head(
    const float* __restrict__ pmax, const float* __restrict__ sums3, float count,
    const float* __restrict__ w_fc1, const float* __restrict__ b_fc1,
    const float* __restrict__ w_fc2, const float* __restrict__ b_fc2,
    float* __restrict__ y)
{
    const int b = blockIdx.x, t = threadIdx.x;
    __shared__ float pooled[64];
    __shared__ float hid[32];
    float2 s = stats_from(sums3, b, count);
    pooled[t] = (pmax[(size_t)b * 64 + t] - s.x) * s.y;
    __syncthreads();
    if (t < 32) {
        float h = b_fc1[t];
#pragma unroll
        for (int c = 0; c < 64; c++) h += pooled[c] * w_fc1[t * 64 + c];
        hid[t] = LRELU(h);
    }
    __syncthreads();
    if (t == 0) {
        float v = b_fc2[0];
#pragma unroll
        for (int c = 0; c < 32; c++) v += hid[c] * w_fc2[c];
        y[b] = v;
    }
}

__global__ void sigmoid_diff(const float* __restrict__ y1,
                             const float* __restrict__ y2,
                             float* __restrict__ out)
{
    int b = threadIdx.x;
    if (b < 128) out[b] = 1.0f / (1.0f + expf(-(y1[b] - y2[b])));
}

extern "C" void kernel_launch(void* const* d_in, const int* in_sizes, int n_in,
                              void* d_out, int out_size, void* d_ws, size_t ws_size,
                              hipStream_t stream)
{
    const float* data1 = (const float*)d_in[0];
    const int*   idx1  = (const int*)d_in[1];
    const float* data2 = (const float*)d_in[2];
    const int*   idx2  = (const int*)d_in[3];
    const float* w1 = (const float*)d_in[4];
    const float* b1 = (const float*)d_in[5];
    const float* w2 = (const float*)d_in[6];
    const float* b2 = (const float*)d_in[7];
    const float* w3 = (const float*)d_in[8];
    const float* b3 = (const float*)d_in[9];
    const float* wfc1 = (const float*)d_in[10];
    const float* bfc1 = (const float*)d_in[11];
    const float* wfc2 = (const float*)d_in[12];
    const float* bfc2 = (const float*)d_in[13];

    // xT, a1, a2 all fp8 (1B/elem)
    const size_t needM = (size_t)256 * 1024 * (64 + 256 + 128) + 768 * 1024;
    const bool merged = ws_size >= needM;
    const int nB = merged ? 256 : 128;
    const size_t szXT = (size_t)nB * 1024 * 64;        // fp8
    const size_t szA1 = (size_t)nB * 1024 * 256;       // fp8
    const size_t szA2 = (size_t)nB * 1024 * 128;       // fp8

    char* ws = (char*)d_ws;
    unsigned char* xT8 = (unsigned char*)ws;
    unsigned char* a1  = (unsigned char*)(ws + szXT);
    unsigned char* a2  = (unsigned char*)(ws + szXT + szA1);
    char* tail = ws + szXT + szA1 + szA2;
    unsigned char* wq1f8 = (unsigned char*)tail;                 // 48 KB
    unsigned char* wq2f8 = (unsigned char*)(tail + 128 * 1024);  // 96 KB
    unsigned char* wq3f8 = (unsigned char*)(tail + 384 * 1024);  // 24 KB
    float* sums = (float*)(tail + 448 * 1024);                   // 3*nB*2 f32
    float* pmax = (float*)(tail + 512 * 1024);                   // nB*64 f32
    float* yv   = (float*)(tail + 640 * 1024);                   // 256 f32

    prep_all<<<96, 256, 0, stream>>>(w1, wq1f8, w2, wq2f8, w3, wq3f8);

    const int nIter = merged ? 1 : 2;
    for (int t = 0; t < nIter; ++t) {
        const float* dA = (merged || t == 0) ? data1 : data2;
        const float* dB = merged ? data2 : dA;
        const int* iA = (merged || t == 0) ? idx1 : idx2;
        const int* iB = merged ? idx2 : iA;
        float* s1 = sums;
        float* s2 = sums + nB * 2;
        float* s3 = sums + nB * 4;

        // sums/pmax re-init folded into transpose_in block (0,0)
        transpose_in<<<dim3(16, nB), 256, 0, stream>>>(dA, dB, xT8, sums,
                                                       (unsigned int*)pmax);

        conv1_fp8<<<dim3(nB, 2, 8), 256, 0, stream>>>(
            xT8, iA, iB, wq1f8, b1, a1, s1);

        norm_act_fp8<<<dim3(16, nB), 256, 0, stream>>>(a1, s1, 256.0f * 1024.0f, 16384);

        conv2_fp8<<<dim3(nB, 1, 8), 256, 0, stream>>>(
            a1, iA, iB, wq2f8, b2, a2, s2);

        norm_act_fp8<<<dim3(8, nB), 256, 0, stream>>>(a2, s2, 128.0f * 1024.0f, 8192);

        conv3_fp8<<<dim3(nB, 1, 8), 256, 0, stream>>>(
            a2, iA, iB, wq3f8, b3, s3, pmax);

        fc_head<<<nB, 64, 0, stream>>>(pmax, s3, 64.0f * 1024.0f,
                                       wfc1, bfc1, wfc2, bfc2,
                                       yv + (merged ? 0 : t * 128));
    }
    sigmoid_diff<<<1, 128, 0, stream>>>(yv, yv + 128, (float*)d_out);
}